// Round 9
// baseline (339.356 us; speedup 1.0000x reference)
//
#include <hip/hip_runtime.h>
#include <hip/hip_bf16.h>
#include <math.h>

#define BATCH 32
#define DFEAT 21
#define NPTS 1024
#define KSEL 32
#define NOUT 64

typedef unsigned long long u64;

__device__ __forceinline__ unsigned ord32(float f) {
    unsigned u = __float_as_uint(f);
    return ((int)u >= 0) ? (u | 0x80000000u) : ~u;
}
__device__ __forceinline__ float iord32(unsigned u) {
    unsigned s = (u & 0x80000000u) ? (u & 0x7FFFFFFFu) : ~u;
    return __uint_as_float(s);
}
__device__ __forceinline__ u64 mkkey(unsigned o, int m) {
    return ((u64)o << 32) | (unsigned)(~m);
}

// Dual-stream bitonic sort, descending by u64 key. Element e = lane + 64*i.
// After sort, reg 0 lane r holds rank-r element.
template <int R>
__device__ __forceinline__ void sort2_desc(u64* A, u64* B, int lane) {
    const int NEL = R * 64;
    #pragma unroll
    for (int k = 2; k <= NEL; k <<= 1) {
        #pragma unroll
        for (int j = k >> 1; j >= 1; j >>= 1) {
            if (j >= 64) {
                const int rj = j >> 6;
                #pragma unroll
                for (int i = 0; i < R; ++i) {
                    if ((i & rj) == 0) {
                        const int e = lane + 64 * i;
                        const bool wm = ((e & k) == 0);
                        u64 x = A[i], y = A[i ^ rj];
                        u64 mx = x > y ? x : y, mn = x > y ? y : x;
                        A[i] = wm ? mx : mn; A[i ^ rj] = wm ? mn : mx;
                        x = B[i]; y = B[i ^ rj];
                        mx = x > y ? x : y; mn = x > y ? y : x;
                        B[i] = wm ? mx : mn; B[i ^ rj] = wm ? mn : mx;
                    }
                }
            } else {
                #pragma unroll
                for (int i = 0; i < R; ++i) {
                    const int e = lane + 64 * i;
                    const bool wm = ((e & j) == 0) == ((e & k) == 0);
                    const u64 oa = __shfl_xor(A[i], j);
                    const u64 ob = __shfl_xor(B[i], j);
                    const u64 mxa = A[i] > oa ? A[i] : oa;
                    const u64 mna = A[i] > oa ? oa : A[i];
                    A[i] = wm ? mxa : mna;
                    const u64 mxb = B[i] > ob ? B[i] : ob;
                    const u64 mnb = B[i] > ob ? ob : B[i];
                    B[i] = wm ? mxb : mnb;
                }
            }
        }
    }
}

// Exact rare-path (Ctot > 128, statistically never taken). RECOMPUTES the
// full-range distances from LDS (bit-identical fmaf chain). Returns
// rank-`lane` winner for lane<32.
__device__ __noinline__ u64 knn_fallback(const float* xs, const float* xxs,
                                         int n, int lane) {
    const float4* xs4  = (const float4*)xs;
    const float4* xxs4 = (const float4*)xxs;
    float4 acc[4];
    #pragma unroll
    for (int c = 0; c < 4; ++c) acc[c] = make_float4(0.f, 0.f, 0.f, 0.f);
    for (int d = 0; d < DFEAT; ++d) {
        const float xnd = xs[d * NPTS + n];
        #pragma unroll
        for (int c = 0; c < 4; ++c) {
            const float4 t = xs4[d * 256 + c * 64 + lane];
            acc[c].x = fmaf(t.x, xnd, acc[c].x);
            acc[c].y = fmaf(t.y, xnd, acc[c].y);
            acc[c].z = fmaf(t.z, xnd, acc[c].z);
            acc[c].w = fmaf(t.w, xnd, acc[c].w);
        }
    }
    const float xxn = xxs[n];
    unsigned ord[16];
    #pragma unroll
    for (int c = 0; c < 4; ++c) {
        const float4 xm = xxs4[c * 64 + lane];
        ord[c * 4 + 0] = ord32((2.f * acc[c].x - xxn) - xm.x);
        ord[c * 4 + 1] = ord32((2.f * acc[c].y - xxn) - xm.y);
        ord[c * 4 + 2] = ord32((2.f * acc[c].z - xxn) - xm.z);
        ord[c * 4 + 3] = ord32((2.f * acc[c].w - xxn) - xm.w);
    }
    u64 W = ~0ULL, win = 0ULL;
    for (int it = 0; it < 32; ++it) {
        u64 best = 0ULL;
        #pragma unroll
        for (int i = 0; i < 16; ++i) {
            const int m = (i >> 2) * 256 + lane * 4 + (i & 3);
            const u64 k = mkkey(ord[i], m);
            if (k < W && k > best) best = k;
        }
        #pragma unroll
        for (int off = 32; off >= 1; off >>= 1) {
            const u64 o = __shfl_xor(best, off);
            best = o > best ? o : best;
        }
        win = (lane == it) ? best : win;
        W = best;
    }
    return win;
}

#define ORD8(O, A0, A1, XXN) \
    O[0] = ord32((2.f * A0.x - XXN) - xm0.x); \
    O[1] = ord32((2.f * A0.y - XXN) - xm0.y); \
    O[2] = ord32((2.f * A0.z - XXN) - xm0.z); \
    O[3] = ord32((2.f * A0.w - XXN) - xm0.w); \
    O[4] = ord32((2.f * A1.x - XXN) - xm1.x); \
    O[5] = ord32((2.f * A1.y - XXN) - xm1.y); \
    O[6] = ord32((2.f * A1.z - XXN) - xm1.z); \
    O[7] = ord32((2.f * A1.w - XXN) - xm1.w);

// ---------------------------------------------------------------------------
// Kernel 1: per-row KNN with wave-pair cooperative distance. Wave pair
// (q,h=0)/(q,h=1): each wave computes its m-half for 4 rows (each m-side
// b128 read feeds 4 rows; FMA per row halved), exchanges the partner-owned
// rows' ord values via LDS, then owns 2 rows FULL-range and runs the proven
// R8 extraction verbatim (u32 value threshold -> compact -> exact u64 dual
// bitonic sort). State per lane identical to R8 (32 acc -> 32 ord).
// grid 256 (32 b x 8 chunks), block 1024 (16 waves), static LDS 152 KB.
// ---------------------------------------------------------------------------
__global__ __launch_bounds__(1024)
__attribute__((amdgpu_waves_per_eu(4, 4)))
void knn_kernel(
        const float* __restrict__ x,
        int* __restrict__ idx_ws, float* __restrict__ dist_ws,
        float* __restrict__ sub_ws) {
    __shared__ __align__(16) float xs[DFEAT * NPTS];      // 84 KB
    __shared__ __align__(16) float xxs[NPTS];             // 4 KB
    __shared__ __align__(16) unsigned exbuf[8 * 4 * 512]; // 64 KB (EX / cand)

    u64*   cand = (u64*)exbuf;
    uint4* EX4  = (uint4*)exbuf;

    const int tid  = threadIdx.x;
    const int lane = tid & 63;
    const int w    = tid >> 6;
    const int q    = w >> 1;     // pair id 0..7
    const int h    = w & 1;      // m-half id
    const int b      = blockIdx.x >> 3;
    const int nchunk = blockIdx.x & 7;

    {
        const float4* xb4 = (const float4*)(x + (size_t)b * DFEAT * NPTS);
        float4* xsw = (float4*)xs;
        for (int i = tid; i < DFEAT * 256; i += 1024) xsw[i] = xb4[i];
    }
    __syncthreads();
    {
        float s = 0.f;
        #pragma unroll
        for (int d = 0; d < DFEAT; ++d) { float v = xs[d * NPTS + tid]; s = fmaf(v, v, s); }
        xxs[tid] = s;
    }

    u64* cwA = cand + (w * 2 + 0) * 128;
    u64* cwB = cand + (w * 2 + 1) * 128;
    const float4* xs4  = (const float4*)xs;
    const float4* xxs4 = (const float4*)xxs;
    const int nbase = nchunk * 128 + q * 16;
    const int hoff  = h * 128;    // float4-unit offset of this wave's m-half

    for (int it = 0; it < 4; ++it) {
        __syncthreads();   // EX region free of prior iteration's sort reads
        const int n0 = nbase + it * 4;

        // ---- distances: this wave's m-half for 4 rows; each t feeds 4 rows
        float4 a00 = make_float4(0.f,0.f,0.f,0.f), a01 = a00;
        float4 a10 = a00, a11 = a00, a20 = a00, a21 = a00, a30 = a00, a31 = a00;
        for (int d = 0; d < DFEAT; ++d) {
            const float4 xn = *(const float4*)(xs + d * NPTS + n0);
            const float4 t0 = xs4[d * 256 + hoff + lane];
            const float4 t1 = xs4[d * 256 + hoff + 64 + lane];
            a00.x = fmaf(t0.x, xn.x, a00.x); a00.y = fmaf(t0.y, xn.x, a00.y);
            a00.z = fmaf(t0.z, xn.x, a00.z); a00.w = fmaf(t0.w, xn.x, a00.w);
            a01.x = fmaf(t1.x, xn.x, a01.x); a01.y = fmaf(t1.y, xn.x, a01.y);
            a01.z = fmaf(t1.z, xn.x, a01.z); a01.w = fmaf(t1.w, xn.x, a01.w);
            a10.x = fmaf(t0.x, xn.y, a10.x); a10.y = fmaf(t0.y, xn.y, a10.y);
            a10.z = fmaf(t0.z, xn.y, a10.z); a10.w = fmaf(t0.w, xn.y, a10.w);
            a11.x = fmaf(t1.x, xn.y, a11.x); a11.y = fmaf(t1.y, xn.y, a11.y);
            a11.z = fmaf(t1.z, xn.y, a11.z); a11.w = fmaf(t1.w, xn.y, a11.w);
            a20.x = fmaf(t0.x, xn.z, a20.x); a20.y = fmaf(t0.y, xn.z, a20.y);
            a20.z = fmaf(t0.z, xn.z, a20.z); a20.w = fmaf(t0.w, xn.z, a20.w);
            a21.x = fmaf(t1.x, xn.z, a21.x); a21.y = fmaf(t1.y, xn.z, a21.y);
            a21.z = fmaf(t1.z, xn.z, a21.z); a21.w = fmaf(t1.w, xn.z, a21.w);
            a30.x = fmaf(t0.x, xn.w, a30.x); a30.y = fmaf(t0.y, xn.w, a30.y);
            a30.z = fmaf(t0.z, xn.w, a30.z); a30.w = fmaf(t0.w, xn.w, a30.w);
            a31.x = fmaf(t1.x, xn.w, a31.x); a31.y = fmaf(t1.y, xn.w, a31.y);
            a31.z = fmaf(t1.z, xn.w, a31.z); a31.w = fmaf(t1.w, xn.w, a31.w);
        }
        const float4 xm0 = xxs4[hoff + lane];
        const float4 xm1 = xxs4[hoff + 64 + lane];
        const float4 xxn = *(const float4*)(xxs + n0);
        unsigned o0[8], o1[8], o2[8], o3[8];
        ORD8(o0, a00, a01, xxn.x)
        ORD8(o1, a10, a11, xxn.y)
        ORD8(o2, a20, a21, xxn.z)
        ORD8(o3, a30, a31, xxn.w)

        // ---- EX write: partner-owned rows' ords (this wave's half) ----
        {
            const int sp = 2 - 2 * h;     // first partner-owned row (local)
            const unsigned* pa = (h == 0) ? o2 : o0;
            const unsigned* pb = (h == 0) ? o3 : o1;
            uint4 v;
            v.x = pa[0]; v.y = pa[1]; v.z = pa[2]; v.w = pa[3];
            EX4[(q * 4 + sp) * 128 + lane] = v;
            v.x = pa[4]; v.y = pa[5]; v.z = pa[6]; v.w = pa[7];
            EX4[(q * 4 + sp) * 128 + 64 + lane] = v;
            v.x = pb[0]; v.y = pb[1]; v.z = pb[2]; v.w = pb[3];
            EX4[(q * 4 + sp + 1) * 128 + lane] = v;
            v.x = pb[4]; v.y = pb[5]; v.z = pb[6]; v.w = pb[7];
            EX4[(q * 4 + sp + 1) * 128 + 64 + lane] = v;
        }
        __syncthreads();

        // ---- assemble full-range ord for the 2 owned rows ----
        const int na = n0 + 2 * h;
        const int nb = na + 1;
        unsigned ordA[16], ordB[16];
        {
            const unsigned* oa = (h == 0) ? o0 : o2;
            const unsigned* ob = (h == 0) ? o1 : o3;
            const int ownbase = h * 8;        // slots of own c_g
            const int pbase   = 8 - h * 8;    // slots of partner c_g
            #pragma unroll
            for (int i = 0; i < 8; ++i) { ordA[ownbase + i] = oa[i]; ordB[ownbase + i] = ob[i]; }
            uint4 p;
            p = EX4[(q * 4 + 2 * h) * 128 + lane];
            ordA[pbase + 0] = p.x; ordA[pbase + 1] = p.y;
            ordA[pbase + 2] = p.z; ordA[pbase + 3] = p.w;
            p = EX4[(q * 4 + 2 * h) * 128 + 64 + lane];
            ordA[pbase + 4] = p.x; ordA[pbase + 5] = p.y;
            ordA[pbase + 6] = p.z; ordA[pbase + 7] = p.w;
            p = EX4[(q * 4 + 2 * h + 1) * 128 + lane];
            ordB[pbase + 0] = p.x; ordB[pbase + 1] = p.y;
            ordB[pbase + 2] = p.z; ordB[pbase + 3] = p.w;
            p = EX4[(q * 4 + 2 * h + 1) * 128 + 64 + lane];
            ordB[pbase + 4] = p.x; ordB[pbase + 5] = p.y;
            ordB[pbase + 6] = p.z; ordB[pbase + 7] = p.w;
        }
        __syncthreads();   // all EX reads done; cand (aliased) may be written

        // ======== from here: R8's proven extraction, verbatim ========
        unsigned va = ordA[0], vb = ordB[0];
        #pragma unroll
        for (int i = 1; i < 16; ++i) {
            va = ordA[i] > va ? ordA[i] : va;
            vb = ordB[i] > vb ? ordB[i] : vb;
        }
        #pragma unroll
        for (int kk = 2; kk <= 64; kk <<= 1) {
            #pragma unroll
            for (int j = kk >> 1; j >= 1; j >>= 1) {
                const unsigned oa = __shfl_xor(va, j);
                const unsigned ob = __shfl_xor(vb, j);
                const bool up      = ((lane & kk) == 0);
                const bool upper   = ((lane & j) != 0);
                const bool takeMax = (upper == up);
                va = (takeMax ? (oa > va) : (oa < va)) ? oa : va;
                vb = (takeMax ? (ob > vb) : (ob < vb)) ? ob : vb;
            }
        }
        const unsigned Ta = __shfl(va, 32);
        const unsigned Tb = __shfl(vb, 32);

        int ca = 0, cb = 0;
        #pragma unroll
        for (int i = 0; i < 16; ++i) {
            ca += (ordA[i] >= Ta) ? 1 : 0;
            cb += (ordB[i] >= Tb) ? 1 : 0;
        }
        int sa = ca, sb = cb;
        #pragma unroll
        for (int off = 1; off < 64; off <<= 1) {
            const int t2a = __shfl_up(sa, off);
            const int t2b = __shfl_up(sb, off);
            if (lane >= off) { sa += t2a; sb += t2b; }
        }
        const int baseA = sa - ca, baseB = sb - cb;
        const int CtA = __shfl(sa, 63), CtB = __shfl(sb, 63);

        {
            int p = baseA;
            #pragma unroll
            for (int i = 0; i < 16; ++i) {
                const int m = (i >> 2) * 256 + lane * 4 + (i & 3);
                if (ordA[i] >= Ta) { if (p < 128) cwA[p] = mkkey(ordA[i], m); ++p; }
            }
            p = baseB;
            #pragma unroll
            for (int i = 0; i < 16; ++i) {
                const int m = (i >> 2) * 256 + lane * 4 + (i & 3);
                if (ordB[i] >= Tb) { if (p < 128) cwB[p] = mkkey(ordB[i], m); ++p; }
            }
        }
        __asm__ volatile("s_waitcnt lgkmcnt(0)" ::: "memory");

        u64 keyA, keyB;
        if (CtA <= 128 && CtB <= 128) {
            if (CtA <= 64 && CtB <= 64) {
                u64 a0 = (lane < CtA) ? cwA[lane] : 0ULL;
                u64 b0 = (lane < CtB) ? cwB[lane] : 0ULL;
                sort2_desc<1>(&a0, &b0, lane);
                keyA = a0; keyB = b0;
            } else {
                u64 a[2], bb[2];
                #pragma unroll
                for (int i = 0; i < 2; ++i) {
                    const int ci = lane + 64 * i;
                    a[i]  = (ci < CtA) ? cwA[ci] : 0ULL;
                    bb[i] = (ci < CtB) ? cwB[ci] : 0ULL;
                }
                sort2_desc<2>(a, bb, lane);
                keyA = a[0]; keyB = bb[0];
            }
        } else {
            keyA = knn_fallback(xs, xxs, na, lane);
            keyB = knn_fallback(xs, xxs, nb, lane);
        }

        const int   mA = (int)(~(unsigned)keyA);
        const int   mB = (int)(~(unsigned)keyB);
        const float pdA = iord32((unsigned)(keyA >> 32));
        const float pdB = iord32((unsigned)(keyB >> 32));
        const float xxna = (h == 0) ? xxn.x : xxn.z;
        const float xxnb = (h == 0) ? xxn.y : xxn.w;
        if (lane < KSEL) {
            const size_t oA = ((size_t)(b * NPTS + na)) * KSEL + lane;
            const size_t oB = ((size_t)(b * NPTS + nb)) * KSEL + lane;
            idx_ws[oA]  = mA;          idx_ws[oB]  = mB;
            dist_ws[oA] = -pdA;        dist_ws[oB] = -pdB;
            sub_ws[oA]  = 0.5f * ((pdA + xxs[mA]) + xxna);
            sub_ws[oB]  = 0.5f * ((pdB + xxs[mB]) + xxnb);
        }
    }
}

// ---------------------------------------------------------------------------
// Kernel 2: partial Gram of q = sub^2 over 128-row chunks.
// grid 256 (b x 8), block 256 (k = t/8, 4 j's per thread).
// ---------------------------------------------------------------------------
__global__ __launch_bounds__(256) void norm_part_kernel(
        const float* __restrict__ sub_ws, float* __restrict__ npart) {
    __shared__ float qS[128 * 33];
    const int tid = threadIdx.x;
    const int bc = blockIdx.x;
    const float* sb = sub_ws + (size_t)bc * 128 * KSEL;
    for (int i = tid; i < 128 * 32; i += 256) {
        const float v = sb[i];
        qS[(i >> 5) * 33 + (i & 31)] = v * v;
    }
    __syncthreads();
    const int k = tid >> 3, jg = tid & 7;
    float a0 = 0.f, a1 = 0.f, a2 = 0.f, a3 = 0.f;
    for (int n = 0; n < 128; ++n) {
        const float qk = qS[n * 33 + k];
        a0 = fmaf(qk, qS[n * 33 + jg], a0);
        a1 = fmaf(qk, qS[n * 33 + jg + 8], a1);
        a2 = fmaf(qk, qS[n * 33 + jg + 16], a2);
        a3 = fmaf(qk, qS[n * 33 + jg + 24], a3);
    }
    float* op = npart + (size_t)bc * 1024 + k * 32 + jg;
    op[0] = a0; op[8] = a1; op[16] = a2; op[24] = a3;
}

// ---------------------------------------------------------------------------
// Kernel 3: combine 8 chunk-partials -> recip = 1/max(sqrt(norm2),1e-12).
// grid 32, block 1024.
// ---------------------------------------------------------------------------
__global__ __launch_bounds__(1024) void norm_combine_kernel(
        const float* __restrict__ npart, float* __restrict__ recip_ws) {
    const int b = blockIdx.x, t = threadIdx.x;
    float s = 0.f;
    #pragma unroll
    for (int c = 0; c < 8; ++c)
        s += npart[((size_t)(b * 8 + c)) * 1024 + t];
    recip_ws[(size_t)b * NPTS + t] = 1.0f / fmaxf(sqrtf(s), 1e-12f);
}

// ---------------------------------------------------------------------------
// Kernel 4: gm_red + BN1/BN2 f64 partial sums. 32 rows per block.
// grid 1024 (b x 32), block 256.
// ---------------------------------------------------------------------------
__global__ __launch_bounds__(256) void gmred_kernel(
        const float* __restrict__ sub_ws, const float* __restrict__ dist_ws,
        const float* __restrict__ recip_ws, const float* __restrict__ w_gm,
        float* __restrict__ gmred_ws, double* __restrict__ part12) {
    __shared__ float subS[32 * 32];
    __shared__ float subWS[32 * 32];
    __shared__ double redS[4][4];

    const int tid = threadIdx.x;
    const int b   = blockIdx.x >> 5;
    const int n0  = (blockIdx.x & 31) * 32;

    {
        const float4 wv = ((const float4*)w_gm)[tid & 7];
        const float4 sv = ((const float4*)(sub_ws + ((size_t)(b * NPTS + n0)) * KSEL))[tid];
        ((float4*)subS)[tid] = sv;
        float4 t;
        t.x = sv.x * wv.x; t.y = sv.y * wv.y; t.z = sv.z * wv.z; t.w = sv.w * wv.w;
        ((float4*)subWS)[tid] = t;
    }
    const int k = tid & 31, rg = tid >> 5;
    float rk[32];
    {
        const float4* rp = (const float4*)(recip_ws + (size_t)b * NPTS + k * 32);
        #pragma unroll
        for (int c4 = 0; c4 < 8; ++c4) {
            const float4 v = rp[c4];
            rk[c4 * 4 + 0] = v.x; rk[c4 * 4 + 1] = v.y;
            rk[c4 * 4 + 2] = v.z; rk[c4 * 4 + 3] = v.w;
        }
    }
    __syncthreads();

    float sacc[4] = {0.f, 0.f, 0.f, 0.f};
    const float4* swp = (const float4*)subWS;
    #pragma unroll
    for (int c4 = 0; c4 < 8; ++c4) {
        #pragma unroll
        for (int i = 0; i < 4; ++i) {
            const float4 sw = swp[(rg * 4 + i) * 8 + c4];
            sacc[i] = fmaf(sw.x, rk[c4 * 4 + 0], sacc[i]);
            sacc[i] = fmaf(sw.y, rk[c4 * 4 + 1], sacc[i]);
            sacc[i] = fmaf(sw.z, rk[c4 * 4 + 2], sacc[i]);
            sacc[i] = fmaf(sw.w, rk[c4 * 4 + 3], sacc[i]);
        }
    }

    double s1 = 0, s2 = 0, s3 = 0, s4 = 0;
    #pragma unroll
    for (int i = 0; i < 4; ++i) {
        const int rl = rg * 4 + i;
        const float g = subS[rl * 32 + k] * sacc[i];
        const size_t row = (size_t)(b * NPTS + n0 + rl);
        gmred_ws[row * KSEL + k] = g;
        const float dv = dist_ws[row * KSEL + k];
        s1 += (double)dv; s2 = fma((double)dv, (double)dv, s2);
        s3 += (double)g;  s4 = fma((double)g, (double)g, s4);
    }
    #pragma unroll
    for (int off = 32; off >= 1; off >>= 1) {
        s1 += __shfl_xor(s1, off);
        s2 += __shfl_xor(s2, off);
        s3 += __shfl_xor(s3, off);
        s4 += __shfl_xor(s4, off);
    }
    if ((tid & 63) == 0) {
        const int wv = tid >> 6;
        redS[wv][0] = s1; redS[wv][1] = s2; redS[wv][2] = s3; redS[wv][3] = s4;
    }
    __syncthreads();
    if (tid == 0) {
        double a0 = 0, a1 = 0, a2 = 0, a3 = 0;
        #pragma unroll
        for (int wv = 0; wv < 4; ++wv) {
            a0 += redS[wv][0]; a1 += redS[wv][1]; a2 += redS[wv][2]; a3 += redS[wv][3];
        }
        part12[(size_t)blockIdx.x * 4 + 0] = a0;
        part12[(size_t)blockIdx.x * 4 + 1] = a1;
        part12[(size_t)blockIdx.x * 4 + 2] = a2;
        part12[(size_t)blockIdx.x * 4 + 3] = a3;
    }
}

// ---------------------------------------------------------------------------
// Kernel 5: uc[b,n,o] = sum_d w_up[o,d] * x[b,d,n]. grid 512, block 256.
// ---------------------------------------------------------------------------
__global__ __launch_bounds__(256) void uc_kernel(
        const float* __restrict__ x, const float* __restrict__ w_up,
        float* __restrict__ uc_ws) {
    __shared__ float wS[NOUT * DFEAT];
    const int tid = threadIdx.x, lane = tid & 63, w = tid >> 6;
    const int b  = blockIdx.x >> 4;
    const int n0 = (blockIdx.x & 15) * 64;
    for (int i = tid; i < NOUT * DFEAT; i += 256) wS[i] = w_up[i];
    __syncthreads();
    float wr[DFEAT];
    #pragma unroll
    for (int d = 0; d < DFEAT; ++d) wr[d] = wS[lane * DFEAT + d];
    const float* xb = x + (size_t)b * DFEAT * NPTS;
    for (int g = 0; g < 4; ++g) {
        const int nn = __builtin_amdgcn_readfirstlane(n0 + w * 16 + g * 4);
        float a0 = 0.f, a1 = 0.f, a2 = 0.f, a3 = 0.f;
        #pragma unroll
        for (int d = 0; d < DFEAT; ++d) {
            const float* xp = xb + d * NPTS + nn;
            const float wd = wr[d];
            a0 = fmaf(wd, xp[0], a0);
            a1 = fmaf(wd, xp[1], a1);
            a2 = fmaf(wd, xp[2], a2);
            a3 = fmaf(wd, xp[3], a3);
        }
        float* op = uc_ws + ((size_t)(b * NPTS) + nn) * NOUT + lane;
        op[0 * NOUT] = a0; op[1 * NOUT] = a1; op[2 * NOUT] = a2; op[3 * NOUT] = a3;
    }
}

// ---------------------------------------------------------------------------
// Kernel 6: reduce BN1/BN2 partials -> folded scale/offset consts. grid 1.
// ---------------------------------------------------------------------------
__global__ __launch_bounds__(256) void reduce12_kernel(
        const double* __restrict__ part12, int nblocks,
        const float* __restrict__ w_dist,
        const float* __restrict__ g1, const float* __restrict__ b1,
        const float* __restrict__ g2, const float* __restrict__ b2,
        float* __restrict__ consts) {
    __shared__ double S[256][4];
    const int t = threadIdx.x;
    double a0 = 0, a1 = 0, a2 = 0, a3 = 0;
    for (int i = t; i < nblocks; i += 256) {
        a0 += part12[(size_t)i * 4 + 0];
        a1 += part12[(size_t)i * 4 + 1];
        a2 += part12[(size_t)i * 4 + 2];
        a3 += part12[(size_t)i * 4 + 3];
    }
    S[t][0] = a0; S[t][1] = a1; S[t][2] = a2; S[t][3] = a3;
    __syncthreads();
    for (int off = 128; off >= 1; off >>= 1) {
        if (t < off) {
            S[t][0] += S[t + off][0]; S[t][1] += S[t + off][1];
            S[t][2] += S[t + off][2]; S[t][3] += S[t + off][3];
        }
        __syncthreads();
    }
    if (t == 0) {
        const double M = (double)BATCH * NPTS * KSEL;
        const double E1 = S[0][0] / M, E2 = S[0][1] / M;
        const double wd = (double)w_dist[0];
        const double mean1 = wd * E1;
        const double var1  = wd * wd * (E2 - E1 * E1);
        const double istd1 = 1.0 / sqrt(var1 + 1e-5);
        consts[0] = (float)(wd * istd1 * (double)g1[0]);
        consts[1] = (float)((double)b1[0] - mean1 * istd1 * (double)g1[0]);
        const double F1 = S[0][2] / M, F2 = S[0][3] / M;
        const double var2  = F2 - F1 * F1;
        const double istd2 = 1.0 / sqrt(var2 + 1e-5);
        consts[2] = (float)(istd2 * (double)g2[0]);
        consts[3] = (float)((double)b2[0] - F1 * istd2 * (double)g2[0]);
    }
}

// ---------------------------------------------------------------------------
// Kernel 7: fused gate compute (LDS broadcast, no shuffles) + BN3 partial
// stats. Writes gate_ws for final. grid 2048 (XCD-swizzled), block 256.
// ---------------------------------------------------------------------------
__global__ __launch_bounds__(256) void gate_stats_kernel(
        const float* __restrict__ dist_ws, const float* __restrict__ gmred_ws,
        const int* __restrict__ idx_ws, const float* __restrict__ uc_ws,
        const float* __restrict__ consts,
        float* __restrict__ gate_ws, double* __restrict__ part3) {
    __shared__ float gS[4][32];
    const int tid = threadIdx.x, lane = tid & 63, w = tid >> 6;
    const int bid = blockIdx.x;
    const int lbid = (bid & 7) * 256 + (bid >> 3);   // b-groups pinned per XCD
    const int b  = lbid >> 6;
    const int n0 = (lbid & 63) * 16;
    const float A1 = consts[0], C1 = consts[1], A2 = consts[2], C2 = consts[3];
    const float* ucb = uc_ws + (size_t)b * NPTS * NOUT;
    double sum = 0.0, ssq = 0.0;
    for (int rr = 0; rr < 4; ++rr) {
        const int n = __builtin_amdgcn_readfirstlane(n0 + w * 4 + rr);
        const int row = b * NPTS + n;
        if (lane < KSEL) {
            const size_t rbase = (size_t)row * KSEL + lane;
            const float dv = dist_ws[rbase];
            const float gv = gmred_ws[rbase];
            const float w1 = 1.f / (1.f + __expf(-fmaf(dv, A1, C1)));
            const float w2 = 1.f / (1.f + __expf(-fmaf(gv, A2, C2)));
            const float gate = w1 * w2;
            gate_ws[rbase] = gate;
            gS[w][lane] = gate;
        }
        __asm__ volatile("s_waitcnt lgkmcnt(0)" ::: "memory");
        const int* ip = idx_ws + (size_t)row * KSEL;
        const float ucr = ucb[(size_t)n * NOUT + lane];
        float fs = 0.f, fq = 0.f;
        #pragma unroll
        for (int k = 0; k < KSEL; ++k) {
            const float gk = gS[w][k];
            const int   jk = ip[k];
            const float ucn = ucb[(size_t)jk * NOUT + lane];
            const float up  = fmaf(gk, ucn - ucr, ucr);
            fs += up;
            fq = fmaf(up, up, fq);
        }
        sum += (double)fs; ssq += (double)fq;
    }
    __shared__ double p3[4][NOUT][2];
    p3[w][lane][0] = sum; p3[w][lane][1] = ssq;
    __syncthreads();
    if (w == 0) {
        const double s = p3[0][lane][0] + p3[1][lane][0] + p3[2][lane][0] + p3[3][lane][0];
        const double q = p3[0][lane][1] + p3[1][lane][1] + p3[2][lane][1] + p3[3][lane][1];
        part3[((size_t)bid * NOUT + lane) * 2 + 0] = s;
        part3[((size_t)bid * NOUT + lane) * 2 + 1] = q;
    }
}

// ---------------------------------------------------------------------------
// Kernel 8: reduce BN3 partials -> per-channel A/C. grid 64 (one per o).
// ---------------------------------------------------------------------------
__global__ __launch_bounds__(256) void reduce3_kernel(
        const double* __restrict__ part3,
        const float* __restrict__ g3, const float* __restrict__ b3,
        float* __restrict__ consts3) {
    const int o = blockIdx.x, t = threadIdx.x;
    double s = 0, q = 0;
    for (int i = t; i < 2048; i += 256) {
        s += part3[((size_t)i * NOUT + o) * 2 + 0];
        q += part3[((size_t)i * NOUT + o) * 2 + 1];
    }
    __shared__ double S[256][2];
    S[t][0] = s; S[t][1] = q;
    __syncthreads();
    for (int off = 128; off >= 1; off >>= 1) {
        if (t < off) { S[t][0] += S[t + off][0]; S[t][1] += S[t + off][1]; }
        __syncthreads();
    }
    if (t == 0) {
        const double M = (double)BATCH * NPTS * KSEL;
        const double mean = S[0][0] / M;
        const double var  = S[0][1] / M - mean * mean;
        const double istd = 1.0 / sqrt(var + 1e-5);
        consts3[o]        = (float)(istd * (double)g3[o]);
        consts3[64 + o]   = (float)((double)b3[o] - mean * istd * (double)g3[o]);
    }
}

// ---------------------------------------------------------------------------
// Kernel 9: out[b,o,n] = mean_k lrelu(up*A[o]+C[o]). LDS-staged coalesced
// float4 stores. grid 2048 (XCD-swizzled), block 256.
// ---------------------------------------------------------------------------
__global__ __launch_bounds__(256) void final_kernel(
        const float* __restrict__ gate_ws, const int* __restrict__ idx_ws,
        const float* __restrict__ uc_ws, const float* __restrict__ consts3,
        float* __restrict__ out) {
    __shared__ float buf[16 * 65];
    const int tid = threadIdx.x, lane = tid & 63, w = tid >> 6;
    const int bid = blockIdx.x;
    const int lbid = (bid & 7) * 256 + (bid >> 3);
    const int b  = lbid >> 6;
    const int n0 = (lbid & 63) * 16;
    const float* ucb = uc_ws + (size_t)b * NPTS * NOUT;
    const float A = consts3[lane], C = consts3[64 + lane];
    for (int rr = 0; rr < 4; ++rr) {
        const int n = __builtin_amdgcn_readfirstlane(n0 + w * 4 + rr);
        const int row = b * NPTS + n;
        const float* gp = gate_ws + (size_t)row * KSEL;
        const int*   ip = idx_ws  + (size_t)row * KSEL;
        const float ucr = ucb[(size_t)n * NOUT + lane];
        float acc = 0.f;
        #pragma unroll
        for (int k = 0; k < KSEL; ++k) {
            const float gk = gp[k];
            const int   jk = ip[k];
            const float ucn = ucb[(size_t)jk * NOUT + lane];
            const float up  = fmaf(gk, ucn - ucr, ucr);
            float z = fmaf(up, A, C);
            z = (z >= 0.f) ? z : 0.02f * z;
            acc += z;
        }
        buf[(w * 4 + rr) * 65 + lane] = acc * (1.f / 32.f);
    }
    __syncthreads();
    const int o = tid >> 2, g = tid & 3;
    float4 v;
    v.x = buf[(g * 4 + 0) * 65 + o];
    v.y = buf[(g * 4 + 1) * 65 + o];
    v.z = buf[(g * 4 + 2) * 65 + o];
    v.w = buf[(g * 4 + 3) * 65 + o];
    float4* op = (float4*)(out + (size_t)b * NOUT * NPTS + (size_t)o * NPTS + n0);
    op[g] = v;
}

// ---------------------------------------------------------------------------
extern "C" void kernel_launch(void* const* d_in, const int* in_sizes, int n_in,
                              void* d_out, int out_size, void* d_ws, size_t ws_size,
                              hipStream_t stream) {
    const float* x      = (const float*)d_in[0];
    const float* w_dist = (const float*)d_in[2];
    const float* g1     = (const float*)d_in[3];
    const float* b1     = (const float*)d_in[4];
    const float* w_gm   = (const float*)d_in[5];
    const float* g2     = (const float*)d_in[6];
    const float* b2     = (const float*)d_in[7];
    const float* w_up   = (const float*)d_in[8];
    const float* g3     = (const float*)d_in[9];
    const float* b3     = (const float*)d_in[10];
    float* out = (float*)d_out;

    char* ws = (char*)d_ws;
    int*    idx_ws   = (int*)(ws + 0);                      //  0- 4 MB
    float*  dist_ws  = (float*)(ws + ((size_t)4 << 20));    //  4- 8 MB
    float*  sub_ws   = (float*)(ws + ((size_t)8 << 20));    //  8-12 MB (part3 later)
    float*  gmred_ws = (float*)(ws + ((size_t)12 << 20));   // 12-16 MB
    float*  gate_ws  = (float*)(ws + ((size_t)16 << 20));   // 16-20 MB (npart early)
    float*  uc_ws    = (float*)(ws + ((size_t)20 << 20));   // 20-28 MB
    float*  recip_ws = (float*)(ws + ((size_t)28 << 20));
    double* part12   = (double*)(ws + ((size_t)28 << 20) + 0x20000);
    float*  consts   = (float*)(ws + ((size_t)28 << 20) + 0x60000);
    float*  consts3  = consts + 8;
    float*  npart    = gate_ws;            // consumed before gate_stats writes
    double* part3    = (double*)sub_ws;    // sub_ws retired after gmred reads it

    knn_kernel<<<dim3(256), dim3(1024), 0, stream>>>(x, idx_ws, dist_ws, sub_ws);
    norm_part_kernel<<<dim3(256), dim3(256), 0, stream>>>(sub_ws, npart);
    norm_combine_kernel<<<dim3(32), dim3(1024), 0, stream>>>(npart, recip_ws);
    uc_kernel<<<dim3(512), dim3(256), 0, stream>>>(x, w_up, uc_ws);
    gmred_kernel<<<dim3(1024), dim3(256), 0, stream>>>(sub_ws, dist_ws, recip_ws, w_gm,
                                                       gmred_ws, part12);
    reduce12_kernel<<<dim3(1), dim3(256), 0, stream>>>(part12, 1024, w_dist, g1, b1, g2, b2,
                                                       consts);
    gate_stats_kernel<<<dim3(2048), dim3(256), 0, stream>>>(dist_ws, gmred_ws, idx_ws, uc_ws,
                                                            consts, gate_ws, part3);
    reduce3_kernel<<<dim3(64), dim3(256), 0, stream>>>(part3, g3, b3, consts3);
    final_kernel<<<dim3(2048), dim3(256), 0, stream>>>(gate_ws, idx_ws, uc_ws, consts3, out);
}

// Round 10
// 136.310 us; speedup vs baseline: 2.4896x; 2.4896x over previous
//
#include <hip/hip_runtime.h>
#include <hip/hip_bf16.h>
#include <math.h>

#define BATCH 32
#define DFEAT 21
#define NPTS 1024
#define KSEL 32
#define NOUT 64

typedef unsigned long long u64;

__device__ __forceinline__ unsigned ord32(float f) {
    unsigned u = __float_as_uint(f);
    return ((int)u >= 0) ? (u | 0x80000000u) : ~u;
}
__device__ __forceinline__ float iord32(unsigned u) {
    unsigned s = (u & 0x80000000u) ? (u & 0x7FFFFFFFu) : ~u;
    return __uint_as_float(s);
}
__device__ __forceinline__ u64 mkkey(unsigned o, int m) {
    return ((u64)o << 32) | (unsigned)(~m);
}

// Dual-stream bitonic sort, descending by u64 key. Element e = lane + 64*i.
// After sort, reg 0 lane r holds rank-r element.
template <int R>
__device__ __forceinline__ void sort2_desc(u64* A, u64* B, int lane) {
    const int NEL = R * 64;
    #pragma unroll
    for (int k = 2; k <= NEL; k <<= 1) {
        #pragma unroll
        for (int j = k >> 1; j >= 1; j >>= 1) {
            if (j >= 64) {
                const int rj = j >> 6;
                #pragma unroll
                for (int i = 0; i < R; ++i) {
                    if ((i & rj) == 0) {
                        const int e = lane + 64 * i;
                        const bool wm = ((e & k) == 0);
                        u64 x = A[i], y = A[i ^ rj];
                        u64 mx = x > y ? x : y, mn = x > y ? y : x;
                        A[i] = wm ? mx : mn; A[i ^ rj] = wm ? mn : mx;
                        x = B[i]; y = B[i ^ rj];
                        mx = x > y ? x : y; mn = x > y ? y : x;
                        B[i] = wm ? mx : mn; B[i ^ rj] = wm ? mn : mx;
                    }
                }
            } else {
                #pragma unroll
                for (int i = 0; i < R; ++i) {
                    const int e = lane + 64 * i;
                    const bool wm = ((e & j) == 0) == ((e & k) == 0);
                    const u64 oa = __shfl_xor(A[i], j);
                    const u64 ob = __shfl_xor(B[i], j);
                    const u64 mxa = A[i] > oa ? A[i] : oa;
                    const u64 mna = A[i] > oa ? oa : A[i];
                    A[i] = wm ? mxa : mna;
                    const u64 mxb = B[i] > ob ? B[i] : ob;
                    const u64 mnb = B[i] > ob ? ob : B[i];
                    B[i] = wm ? mxb : mnb;
                }
            }
        }
    }
}

// Exact rare-path (Ctot > 128, statistically never taken). RECOMPUTES the
// distances from LDS so the hot path does not keep ord[] live across the
// sort. Returns rank-`lane` winner for lane<32.
__device__ __noinline__ u64 knn_fallback(const float* xs, const float* xxs,
                                         int n, int lane) {
    const float4* xs4  = (const float4*)xs;
    const float4* xxs4 = (const float4*)xxs;
    float4 acc[4];
    #pragma unroll
    for (int c = 0; c < 4; ++c) acc[c] = make_float4(0.f, 0.f, 0.f, 0.f);
    for (int d = 0; d < DFEAT; ++d) {
        const float xnd = xs[d * NPTS + n];
        #pragma unroll
        for (int c = 0; c < 4; ++c) {
            const float4 t = xs4[d * 256 + c * 64 + lane];
            acc[c].x = fmaf(t.x, xnd, acc[c].x);
            acc[c].y = fmaf(t.y, xnd, acc[c].y);
            acc[c].z = fmaf(t.z, xnd, acc[c].z);
            acc[c].w = fmaf(t.w, xnd, acc[c].w);
        }
    }
    const float xxn = xxs[n];
    unsigned ord[16];
    #pragma unroll
    for (int c = 0; c < 4; ++c) {
        const float4 xm = xxs4[c * 64 + lane];
        ord[c * 4 + 0] = ord32((2.f * acc[c].x - xxn) - xm.x);
        ord[c * 4 + 1] = ord32((2.f * acc[c].y - xxn) - xm.y);
        ord[c * 4 + 2] = ord32((2.f * acc[c].z - xxn) - xm.z);
        ord[c * 4 + 3] = ord32((2.f * acc[c].w - xxn) - xm.w);
    }
    u64 W = ~0ULL, win = 0ULL;
    for (int it = 0; it < 32; ++it) {
        u64 best = 0ULL;
        #pragma unroll
        for (int i = 0; i < 16; ++i) {
            const int m = (i >> 2) * 256 + lane * 4 + (i & 3);
            const u64 k = mkkey(ord[i], m);
            if (k < W && k > best) best = k;
        }
        #pragma unroll
        for (int off = 32; off >= 1; off >>= 1) {
            const u64 o = __shfl_xor(best, off);
            best = o > best ? o : best;
        }
        win = (lane == it) ? best : win;
        W = best;
    }
    return win;
}

// ---------------------------------------------------------------------------
// Kernel 1: per-row KNN, 2 rows per wave concurrently (the proven spill-free
// envelope at the allocator's hard 64-VGPR choice for 1024-thread blocks).
// u32 value-only threshold prefilter; exact u64 candidate sort. n-side
// float2 broadcast reads. sub via identity <x_m,x_n> = (pd+xx_m+xx_n)/2.
// grid 256 (32 b x 8 chunks), block 1024 (16 waves x 8 rows), LDS 120KB.
// R8 verbatim (71.5 us, WRITE 14 MB, validated).
// ---------------------------------------------------------------------------
__global__ __launch_bounds__(1024)
__attribute__((amdgpu_waves_per_eu(4, 4)))
void knn_kernel(
        const float* __restrict__ x,
        int* __restrict__ idx_ws, float* __restrict__ dist_ws,
        float* __restrict__ sub_ws) {
    extern __shared__ float smem[];
    float* xs  = smem;                         // [21][1024]
    float* xxs = smem + DFEAT * NPTS;          // [1024]
    u64* cand  = (u64*)(smem + (DFEAT + 1) * NPTS);  // [16][2][128]

    const int tid  = threadIdx.x;
    const int lane = tid & 63;
    const int w    = tid >> 6;
    const int b      = blockIdx.x >> 3;
    const int nchunk = blockIdx.x & 7;

    const float* xb = x + (size_t)b * DFEAT * NPTS;
    for (int i = tid; i < DFEAT * NPTS; i += 1024) xs[i] = xb[i];
    __syncthreads();
    {
        float s = 0.f;
        #pragma unroll
        for (int d = 0; d < DFEAT; ++d) { float v = xs[d * NPTS + tid]; s = fmaf(v, v, s); }
        xxs[tid] = s;
    }
    __syncthreads();

    u64* cwA = cand + (w * 2 + 0) * 128;
    u64* cwB = cand + (w * 2 + 1) * 128;
    const float4* xs4  = (const float4*)xs;
    const float4* xxs4 = (const float4*)xxs;

    const int nbase = nchunk * 128 + w * 8;

    for (int rp = 0; rp < 4; ++rp) {
        const int na = nbase + rp * 2;   // even
        const int nb = na + 1;

        // ---- distances for the pair; m-side float4 reads shared ----
        float4 accA[4], accB[4];
        #pragma unroll
        for (int c = 0; c < 4; ++c) {
            accA[c] = make_float4(0.f, 0.f, 0.f, 0.f);
            accB[c] = make_float4(0.f, 0.f, 0.f, 0.f);
        }
        for (int d = 0; d < DFEAT; ++d) {
            const float2 xn2 = *(const float2*)(xs + d * NPTS + na);
            const float xda = xn2.x;
            const float xdb = xn2.y;
            #pragma unroll
            for (int c = 0; c < 4; ++c) {
                const float4 t = xs4[d * 256 + c * 64 + lane];
                accA[c].x = fmaf(t.x, xda, accA[c].x);
                accA[c].y = fmaf(t.y, xda, accA[c].y);
                accA[c].z = fmaf(t.z, xda, accA[c].z);
                accA[c].w = fmaf(t.w, xda, accA[c].w);
                accB[c].x = fmaf(t.x, xdb, accB[c].x);
                accB[c].y = fmaf(t.y, xdb, accB[c].y);
                accB[c].z = fmaf(t.z, xdb, accB[c].z);
                accB[c].w = fmaf(t.w, xdb, accB[c].w);
            }
        }
        const float xxna = xxs[na], xxnb = xxs[nb];
        unsigned ordA[16], ordB[16];
        #pragma unroll
        for (int c = 0; c < 4; ++c) {
            const float4 xm = xxs4[c * 64 + lane];
            ordA[c * 4 + 0] = ord32((2.f * accA[c].x - xxna) - xm.x);
            ordA[c * 4 + 1] = ord32((2.f * accA[c].y - xxna) - xm.y);
            ordA[c * 4 + 2] = ord32((2.f * accA[c].z - xxna) - xm.z);
            ordA[c * 4 + 3] = ord32((2.f * accA[c].w - xxna) - xm.w);
            ordB[c * 4 + 0] = ord32((2.f * accB[c].x - xxnb) - xm.x);
            ordB[c * 4 + 1] = ord32((2.f * accB[c].y - xxnb) - xm.y);
            ordB[c * 4 + 2] = ord32((2.f * accB[c].z - xxnb) - xm.z);
            ordB[c * 4 + 3] = ord32((2.f * accB[c].w - xxnb) - xm.w);
        }

        // ---- per-lane max VALUE (threshold needs no index) ----
        unsigned va = ordA[0], vb = ordB[0];
        #pragma unroll
        for (int i = 1; i < 16; ++i) {
            va = ordA[i] > va ? ordA[i] : va;
            vb = ordB[i] > vb ? ordB[i] : vb;
        }

        // ---- threshold = 32nd largest of 64 lane maxima (u32 bitonic) ----
        #pragma unroll
        for (int kk = 2; kk <= 64; kk <<= 1) {
            #pragma unroll
            for (int j = kk >> 1; j >= 1; j >>= 1) {
                const unsigned oa = __shfl_xor(va, j);
                const unsigned ob = __shfl_xor(vb, j);
                const bool up      = ((lane & kk) == 0);
                const bool upper   = ((lane & j) != 0);
                const bool takeMax = (upper == up);
                va = (takeMax ? (oa > va) : (oa < va)) ? oa : va;
                vb = (takeMax ? (ob > vb) : (ob < vb)) ? ob : vb;
            }
        }
        const unsigned Ta = __shfl(va, 32);
        const unsigned Tb = __shfl(vb, 32);

        // ---- count + exclusive prefix for compaction (u32 compares) ----
        int ca = 0, cb = 0;
        #pragma unroll
        for (int i = 0; i < 16; ++i) {
            ca += (ordA[i] >= Ta) ? 1 : 0;
            cb += (ordB[i] >= Tb) ? 1 : 0;
        }
        int sa = ca, sb = cb;
        #pragma unroll
        for (int off = 1; off < 64; off <<= 1) {
            const int t2a = __shfl_up(sa, off);
            const int t2b = __shfl_up(sb, off);
            if (lane >= off) { sa += t2a; sb += t2b; }
        }
        const int baseA = sa - ca, baseB = sb - cb;
        const int CtA = __shfl(sa, 63), CtB = __shfl(sb, 63);

        // ---- compact candidates to LDS; ordA/ordB die here ----
        {
            int p = baseA;
            #pragma unroll
            for (int i = 0; i < 16; ++i) {
                const int m = (i >> 2) * 256 + lane * 4 + (i & 3);
                if (ordA[i] >= Ta) { if (p < 128) cwA[p] = mkkey(ordA[i], m); ++p; }
            }
            p = baseB;
            #pragma unroll
            for (int i = 0; i < 16; ++i) {
                const int m = (i >> 2) * 256 + lane * 4 + (i & 3);
                if (ordB[i] >= Tb) { if (p < 128) cwB[p] = mkkey(ordB[i], m); ++p; }
            }
        }
        __asm__ volatile("s_waitcnt lgkmcnt(0)" ::: "memory");

        // ---- adaptive dual bitonic top-32 (exact order) ----
        u64 keyA, keyB;
        if (CtA <= 128 && CtB <= 128) {
            if (CtA <= 64 && CtB <= 64) {
                u64 a0 = (lane < CtA) ? cwA[lane] : 0ULL;
                u64 b0 = (lane < CtB) ? cwB[lane] : 0ULL;
                sort2_desc<1>(&a0, &b0, lane);
                keyA = a0; keyB = b0;
            } else {
                u64 a[2], bb[2];
                #pragma unroll
                for (int i = 0; i < 2; ++i) {
                    const int ci = lane + 64 * i;
                    a[i]  = (ci < CtA) ? cwA[ci] : 0ULL;
                    bb[i] = (ci < CtB) ? cwB[ci] : 0ULL;
                }
                sort2_desc<2>(a, bb, lane);
                keyA = a[0]; keyB = bb[0];
            }
        } else {
            keyA = knn_fallback(xs, xxs, na, lane);
            keyB = knn_fallback(xs, xxs, nb, lane);
        }

        // ---- epilogue: lane r (<32) holds rank-r neighbor ----
        const int   mA = (int)(~(unsigned)keyA);
        const int   mB = (int)(~(unsigned)keyB);
        const float pdA = iord32((unsigned)(keyA >> 32));
        const float pdB = iord32((unsigned)(keyB >> 32));
        if (lane < KSEL) {
            const size_t oA = ((size_t)(b * NPTS + na)) * KSEL + lane;
            const size_t oB = ((size_t)(b * NPTS + nb)) * KSEL + lane;
            idx_ws[oA]  = mA;          idx_ws[oB]  = mB;
            dist_ws[oA] = -pdA;        dist_ws[oB] = -pdB;
            sub_ws[oA]  = 0.5f * ((pdA + xxs[mA]) + xxna);
            sub_ws[oB]  = 0.5f * ((pdB + xxs[mB]) + xxnb);
        }
    }
}

// ---------------------------------------------------------------------------
// Kernel 2: partial Gram of q = sub^2 over 128-row chunks.
// grid 256 (b x 8), block 256 (k = t/8, 4 j's per thread).
// ---------------------------------------------------------------------------
__global__ __launch_bounds__(256) void norm_part_kernel(
        const float* __restrict__ sub_ws, float* __restrict__ npart) {
    __shared__ float qS[128 * 33];
    const int tid = threadIdx.x;
    const int bc = blockIdx.x;
    const float* sb = sub_ws + (size_t)bc * 128 * KSEL;
    for (int i = tid; i < 128 * 32; i += 256) {
        const float v = sb[i];
        qS[(i >> 5) * 33 + (i & 31)] = v * v;
    }
    __syncthreads();
    const int k = tid >> 3, jg = tid & 7;
    float a0 = 0.f, a1 = 0.f, a2 = 0.f, a3 = 0.f;
    for (int n = 0; n < 128; ++n) {
        const float qk = qS[n * 33 + k];
        a0 = fmaf(qk, qS[n * 33 + jg], a0);
        a1 = fmaf(qk, qS[n * 33 + jg + 8], a1);
        a2 = fmaf(qk, qS[n * 33 + jg + 16], a2);
        a3 = fmaf(qk, qS[n * 33 + jg + 24], a3);
    }
    float* op = npart + (size_t)bc * 1024 + k * 32 + jg;
    op[0] = a0; op[8] = a1; op[16] = a2; op[24] = a3;
}

// ---------------------------------------------------------------------------
// Kernel 3: combine 8 chunk-partials -> recip = 1/max(sqrt(norm2),1e-12).
// grid 32, block 1024.
// ---------------------------------------------------------------------------
__global__ __launch_bounds__(1024) void norm_combine_kernel(
        const float* __restrict__ npart, float* __restrict__ recip_ws) {
    const int b = blockIdx.x, t = threadIdx.x;
    float s = 0.f;
    #pragma unroll
    for (int c = 0; c < 8; ++c)
        s += npart[((size_t)(b * 8 + c)) * 1024 + t];
    recip_ws[(size_t)b * NPTS + t] = 1.0f / fmaxf(sqrtf(s), 1e-12f);
}

// ---------------------------------------------------------------------------
// Kernel 4: gm_red + BN1/BN2 f64 partial sums. 32 rows per block.
// grid 1024 (b x 32), block 256.
// ---------------------------------------------------------------------------
__global__ __launch_bounds__(256) void gmred_kernel(
        const float* __restrict__ sub_ws, const float* __restrict__ dist_ws,
        const float* __restrict__ recip_ws, const float* __restrict__ w_gm,
        float* __restrict__ gmred_ws, double* __restrict__ part12) {
    __shared__ float subS[32 * 32];
    __shared__ float subWS[32 * 32];
    __shared__ double redS[4][4];

    const int tid = threadIdx.x;
    const int b   = blockIdx.x >> 5;
    const int n0  = (blockIdx.x & 31) * 32;

    {
        const float4 wv = ((const float4*)w_gm)[tid & 7];
        const float4 sv = ((const float4*)(sub_ws + ((size_t)(b * NPTS + n0)) * KSEL))[tid];
        ((float4*)subS)[tid] = sv;
        float4 t;
        t.x = sv.x * wv.x; t.y = sv.y * wv.y; t.z = sv.z * wv.z; t.w = sv.w * wv.w;
        ((float4*)subWS)[tid] = t;
    }
    const int k = tid & 31, rg = tid >> 5;
    float rk[32];
    {
        const float4* rp = (const float4*)(recip_ws + (size_t)b * NPTS + k * 32);
        #pragma unroll
        for (int c4 = 0; c4 < 8; ++c4) {
            const float4 v = rp[c4];
            rk[c4 * 4 + 0] = v.x; rk[c4 * 4 + 1] = v.y;
            rk[c4 * 4 + 2] = v.z; rk[c4 * 4 + 3] = v.w;
        }
    }
    __syncthreads();

    float sacc[4] = {0.f, 0.f, 0.f, 0.f};
    const float4* swp = (const float4*)subWS;
    #pragma unroll
    for (int c4 = 0; c4 < 8; ++c4) {
        #pragma unroll
        for (int i = 0; i < 4; ++i) {
            const float4 sw = swp[(rg * 4 + i) * 8 + c4];
            sacc[i] = fmaf(sw.x, rk[c4 * 4 + 0], sacc[i]);
            sacc[i] = fmaf(sw.y, rk[c4 * 4 + 1], sacc[i]);
            sacc[i] = fmaf(sw.z, rk[c4 * 4 + 2], sacc[i]);
            sacc[i] = fmaf(sw.w, rk[c4 * 4 + 3], sacc[i]);
        }
    }

    double s1 = 0, s2 = 0, s3 = 0, s4 = 0;
    #pragma unroll
    for (int i = 0; i < 4; ++i) {
        const int rl = rg * 4 + i;
        const float g = subS[rl * 32 + k] * sacc[i];
        const size_t row = (size_t)(b * NPTS + n0 + rl);
        gmred_ws[row * KSEL + k] = g;
        const float dv = dist_ws[row * KSEL + k];
        s1 += (double)dv; s2 = fma((double)dv, (double)dv, s2);
        s3 += (double)g;  s4 = fma((double)g, (double)g, s4);
    }
    #pragma unroll
    for (int off = 32; off >= 1; off >>= 1) {
        s1 += __shfl_xor(s1, off);
        s2 += __shfl_xor(s2, off);
        s3 += __shfl_xor(s3, off);
        s4 += __shfl_xor(s4, off);
    }
    if ((tid & 63) == 0) {
        const int wv = tid >> 6;
        redS[wv][0] = s1; redS[wv][1] = s2; redS[wv][2] = s3; redS[wv][3] = s4;
    }
    __syncthreads();
    if (tid == 0) {
        double a0 = 0, a1 = 0, a2 = 0, a3 = 0;
        #pragma unroll
        for (int wv = 0; wv < 4; ++wv) {
            a0 += redS[wv][0]; a1 += redS[wv][1]; a2 += redS[wv][2]; a3 += redS[wv][3];
        }
        part12[(size_t)blockIdx.x * 4 + 0] = a0;
        part12[(size_t)blockIdx.x * 4 + 1] = a1;
        part12[(size_t)blockIdx.x * 4 + 2] = a2;
        part12[(size_t)blockIdx.x * 4 + 3] = a3;
    }
}

// ---------------------------------------------------------------------------
// Kernel 5: uc[b,n,o] = sum_d w_up[o,d] * x[b,d,n]. grid 512, block 256.
// ---------------------------------------------------------------------------
__global__ __launch_bounds__(256) void uc_kernel(
        const float* __restrict__ x, const float* __restrict__ w_up,
        float* __restrict__ uc_ws) {
    __shared__ float wS[NOUT * DFEAT];
    const int tid = threadIdx.x, lane = tid & 63, w = tid >> 6;
    const int b  = blockIdx.x >> 4;
    const int n0 = (blockIdx.x & 15) * 64;
    for (int i = tid; i < NOUT * DFEAT; i += 256) wS[i] = w_up[i];
    __syncthreads();
    float wr[DFEAT];
    #pragma unroll
    for (int d = 0; d < DFEAT; ++d) wr[d] = wS[lane * DFEAT + d];
    const float* xb = x + (size_t)b * DFEAT * NPTS;
    for (int g = 0; g < 4; ++g) {
        const int nn = __builtin_amdgcn_readfirstlane(n0 + w * 16 + g * 4);
        float a0 = 0.f, a1 = 0.f, a2 = 0.f, a3 = 0.f;
        #pragma unroll
        for (int d = 0; d < DFEAT; ++d) {
            const float* xp = xb + d * NPTS + nn;
            const float wd = wr[d];
            a0 = fmaf(wd, xp[0], a0);
            a1 = fmaf(wd, xp[1], a1);
            a2 = fmaf(wd, xp[2], a2);
            a3 = fmaf(wd, xp[3], a3);
        }
        float* op = uc_ws + ((size_t)(b * NPTS) + nn) * NOUT + lane;
        op[0 * NOUT] = a0; op[1 * NOUT] = a1; op[2 * NOUT] = a2; op[3 * NOUT] = a3;
    }
}

// ---------------------------------------------------------------------------
// Kernel 6: reduce BN1/BN2 partials -> folded scale/offset consts. grid 1.
// ---------------------------------------------------------------------------
__global__ __launch_bounds__(256) void reduce12_kernel(
        const double* __restrict__ part12, int nblocks,
        const float* __restrict__ w_dist,
        const float* __restrict__ g1, const float* __restrict__ b1,
        const float* __restrict__ g2, const float* __restrict__ b2,
        float* __restrict__ consts) {
    __shared__ double S[256][4];
    const int t = threadIdx.x;
    double a0 = 0, a1 = 0, a2 = 0, a3 = 0;
    for (int i = t; i < nblocks; i += 256) {
        a0 += part12[(size_t)i * 4 + 0];
        a1 += part12[(size_t)i * 4 + 1];
        a2 += part12[(size_t)i * 4 + 2];
        a3 += part12[(size_t)i * 4 + 3];
    }
    S[t][0] = a0; S[t][1] = a1; S[t][2] = a2; S[t][3] = a3;
    __syncthreads();
    for (int off = 128; off >= 1; off >>= 1) {
        if (t < off) {
            S[t][0] += S[t + off][0]; S[t][1] += S[t + off][1];
            S[t][2] += S[t + off][2]; S[t][3] += S[t + off][3];
        }
        __syncthreads();
    }
    if (t == 0) {
        const double M = (double)BATCH * NPTS * KSEL;
        const double E1 = S[0][0] / M, E2 = S[0][1] / M;
        const double wd = (double)w_dist[0];
        const double mean1 = wd * E1;
        const double var1  = wd * wd * (E2 - E1 * E1);
        const double istd1 = 1.0 / sqrt(var1 + 1e-5);
        consts[0] = (float)(wd * istd1 * (double)g1[0]);
        consts[1] = (float)((double)b1[0] - mean1 * istd1 * (double)g1[0]);
        const double F1 = S[0][2] / M, F2 = S[0][3] / M;
        const double var2  = F2 - F1 * F1;
        const double istd2 = 1.0 / sqrt(var2 + 1e-5);
        consts[2] = (float)(istd2 * (double)g2[0]);
        consts[3] = (float)((double)b2[0] - F1 * istd2 * (double)g2[0]);
    }
}

// ---------------------------------------------------------------------------
// Kernel 7: fused gate compute (LDS broadcast, no shuffles) + BN3 partial
// stats. Writes gate_ws for final. grid 2048 (XCD-swizzled), block 256.
// (R9 downstream, validated.)
// ---------------------------------------------------------------------------
__global__ __launch_bounds__(256) void gate_stats_kernel(
        const float* __restrict__ dist_ws, const float* __restrict__ gmred_ws,
        const int* __restrict__ idx_ws, const float* __restrict__ uc_ws,
        const float* __restrict__ consts,
        float* __restrict__ gate_ws, double* __restrict__ part3) {
    __shared__ float gS[4][32];
    const int tid = threadIdx.x, lane = tid & 63, w = tid >> 6;
    const int bid = blockIdx.x;
    const int lbid = (bid & 7) * 256 + (bid >> 3);   // b-groups pinned per XCD
    const int b  = lbid >> 6;
    const int n0 = (lbid & 63) * 16;
    const float A1 = consts[0], C1 = consts[1], A2 = consts[2], C2 = consts[3];
    const float* ucb = uc_ws + (size_t)b * NPTS * NOUT;
    double sum = 0.0, ssq = 0.0;
    for (int rr = 0; rr < 4; ++rr) {
        const int n = __builtin_amdgcn_readfirstlane(n0 + w * 4 + rr);
        const int row = b * NPTS + n;
        if (lane < KSEL) {
            const size_t rbase = (size_t)row * KSEL + lane;
            const float dv = dist_ws[rbase];
            const float gv = gmred_ws[rbase];
            const float w1 = 1.f / (1.f + __expf(-fmaf(dv, A1, C1)));
            const float w2 = 1.f / (1.f + __expf(-fmaf(gv, A2, C2)));
            const float gate = w1 * w2;
            gate_ws[rbase] = gate;
            gS[w][lane] = gate;
        }
        __asm__ volatile("s_waitcnt lgkmcnt(0)" ::: "memory");
        const int* ip = idx_ws + (size_t)row * KSEL;
        const float ucr = ucb[(size_t)n * NOUT + lane];
        float fs = 0.f, fq = 0.f;
        #pragma unroll
        for (int k = 0; k < KSEL; ++k) {
            const float gk = gS[w][k];
            const int   jk = ip[k];
            const float ucn = ucb[(size_t)jk * NOUT + lane];
            const float up  = fmaf(gk, ucn - ucr, ucr);
            fs += up;
            fq = fmaf(up, up, fq);
        }
        sum += (double)fs; ssq += (double)fq;
    }
    __shared__ double p3[4][NOUT][2];
    p3[w][lane][0] = sum; p3[w][lane][1] = ssq;
    __syncthreads();
    if (w == 0) {
        const double s = p3[0][lane][0] + p3[1][lane][0] + p3[2][lane][0] + p3[3][lane][0];
        const double q = p3[0][lane][1] + p3[1][lane][1] + p3[2][lane][1] + p3[3][lane][1];
        part3[((size_t)bid * NOUT + lane) * 2 + 0] = s;
        part3[((size_t)bid * NOUT + lane) * 2 + 1] = q;
    }
}

// ---------------------------------------------------------------------------
// Kernel 8: reduce BN3 partials -> per-channel A/C. grid 64 (one per o).
// ---------------------------------------------------------------------------
__global__ __launch_bounds__(256) void reduce3_kernel(
        const double* __restrict__ part3,
        const float* __restrict__ g3, const float* __restrict__ b3,
        float* __restrict__ consts3) {
    const int o = blockIdx.x, t = threadIdx.x;
    double s = 0, q = 0;
    for (int i = t; i < 2048; i += 256) {
        s += part3[((size_t)i * NOUT + o) * 2 + 0];
        q += part3[((size_t)i * NOUT + o) * 2 + 1];
    }
    __shared__ double S[256][2];
    S[t][0] = s; S[t][1] = q;
    __syncthreads();
    for (int off = 128; off >= 1; off >>= 1) {
        if (t < off) { S[t][0] += S[t + off][0]; S[t][1] += S[t + off][1]; }
        __syncthreads();
    }
    if (t == 0) {
        const double M = (double)BATCH * NPTS * KSEL;
        const double mean = S[0][0] / M;
        const double var  = S[0][1] / M - mean * mean;
        const double istd = 1.0 / sqrt(var + 1e-5);
        consts3[o]        = (float)(istd * (double)g3[o]);
        consts3[64 + o]   = (float)((double)b3[o] - mean * istd * (double)g3[o]);
    }
}

// ---------------------------------------------------------------------------
// Kernel 9: out[b,o,n] = mean_k lrelu(up*A[o]+C[o]). LDS-staged coalesced
// float4 stores. grid 2048 (XCD-swizzled), block 256.
// ---------------------------------------------------------------------------
__global__ __launch_bounds__(256) void final_kernel(
        const float* __restrict__ gate_ws, const int* __restrict__ idx_ws,
        const float* __restrict__ uc_ws, const float* __restrict__ consts3,
        float* __restrict__ out) {
    __shared__ float buf[16 * 65];
    const int tid = threadIdx.x, lane = tid & 63, w = tid >> 6;
    const int bid = blockIdx.x;
    const int lbid = (bid & 7) * 256 + (bid >> 3);
    const int b  = lbid >> 6;
    const int n0 = (lbid & 63) * 16;
    const float* ucb = uc_ws + (size_t)b * NPTS * NOUT;
    const float A = consts3[lane], C = consts3[64 + lane];
    for (int rr = 0; rr < 4; ++rr) {
        const int n = __builtin_amdgcn_readfirstlane(n0 + w * 4 + rr);
        const int row = b * NPTS + n;
        const float* gp = gate_ws + (size_t)row * KSEL;
        const int*   ip = idx_ws  + (size_t)row * KSEL;
        const float ucr = ucb[(size_t)n * NOUT + lane];
        float acc = 0.f;
        #pragma unroll
        for (int k = 0; k < KSEL; ++k) {
            const float gk = gp[k];
            const int   jk = ip[k];
            const float ucn = ucb[(size_t)jk * NOUT + lane];
            const float up  = fmaf(gk, ucn - ucr, ucr);
            float z = fmaf(up, A, C);
            z = (z >= 0.f) ? z : 0.02f * z;
            acc += z;
        }
        buf[(w * 4 + rr) * 65 + lane] = acc * (1.f / 32.f);
    }
    __syncthreads();
    const int o = tid >> 2, g = tid & 3;
    float4 v;
    v.x = buf[(g * 4 + 0) * 65 + o];
    v.y = buf[(g * 4 + 1) * 65 + o];
    v.z = buf[(g * 4 + 2) * 65 + o];
    v.w = buf[(g * 4 + 3) * 65 + o];
    float4* op = (float4*)(out + (size_t)b * NOUT * NPTS + (size_t)o * NPTS + n0);
    op[g] = v;
}

// ---------------------------------------------------------------------------
extern "C" void kernel_launch(void* const* d_in, const int* in_sizes, int n_in,
                              void* d_out, int out_size, void* d_ws, size_t ws_size,
                              hipStream_t stream) {
    const float* x      = (const float*)d_in[0];
    const float* w_dist = (const float*)d_in[2];
    const float* g1     = (const float*)d_in[3];
    const float* b1     = (const float*)d_in[4];
    const float* w_gm   = (const float*)d_in[5];
    const float* g2     = (const float*)d_in[6];
    const float* b2     = (const float*)d_in[7];
    const float* w_up   = (const float*)d_in[8];
    const float* g3     = (const float*)d_in[9];
    const float* b3     = (const float*)d_in[10];
    float* out = (float*)d_out;

    char* ws = (char*)d_ws;
    int*    idx_ws   = (int*)(ws + 0);                      //  0- 4 MB
    float*  dist_ws  = (float*)(ws + ((size_t)4 << 20));    //  4- 8 MB
    float*  sub_ws   = (float*)(ws + ((size_t)8 << 20));    //  8-12 MB (part3 later)
    float*  gmred_ws = (float*)(ws + ((size_t)12 << 20));   // 12-16 MB
    float*  gate_ws  = (float*)(ws + ((size_t)16 << 20));   // 16-20 MB (npart early)
    float*  uc_ws    = (float*)(ws + ((size_t)20 << 20));   // 20-28 MB
    float*  recip_ws = (float*)(ws + ((size_t)28 << 20));
    double* part12   = (double*)(ws + ((size_t)28 << 20) + 0x20000);
    float*  consts   = (float*)(ws + ((size_t)28 << 20) + 0x60000);
    float*  consts3  = consts + 8;
    float*  npart    = gate_ws;            // consumed before gate_stats writes
    double* part3    = (double*)sub_ws;    // sub_ws retired after gmred reads it

    const int knn_lds = (DFEAT + 1) * NPTS * 4 + 16 * 2 * 128 * 8;  // 120 KB

    knn_kernel<<<dim3(256), dim3(1024), knn_lds, stream>>>(x, idx_ws, dist_ws, sub_ws);
    norm_part_kernel<<<dim3(256), dim3(256), 0, stream>>>(sub_ws, npart);
    norm_combine_kernel<<<dim3(32), dim3(1024), 0, stream>>>(npart, recip_ws);
    uc_kernel<<<dim3(512), dim3(256), 0, stream>>>(x, w_up, uc_ws);
    gmred_kernel<<<dim3(1024), dim3(256), 0, stream>>>(sub_ws, dist_ws, recip_ws, w_gm,
                                                       gmred_ws, part12);
    reduce12_kernel<<<dim3(1), dim3(256), 0, stream>>>(part12, 1024, w_dist, g1, b1, g2, b2,
                                                       consts);
    gate_stats_kernel<<<dim3(2048), dim3(256), 0, stream>>>(dist_ws, gmred_ws, idx_ws, uc_ws,
                                                            consts, gate_ws, part3);
    reduce3_kernel<<<dim3(64), dim3(256), 0, stream>>>(part3, g3, b3, consts3);
    final_kernel<<<dim3(2048), dim3(256), 0, stream>>>(gate_ws, idx_ws, uc_ws, consts3, out);
}

// Round 11
// 130.091 us; speedup vs baseline: 2.6086x; 1.0478x over previous
//
#include <hip/hip_runtime.h>
#include <hip/hip_bf16.h>
#include <math.h>

#define BATCH 32
#define DFEAT 21
#define NPTS 1024
#define KSEL 32
#define NOUT 64

typedef unsigned long long u64;

__device__ __forceinline__ unsigned ord32(float f) {
    unsigned u = __float_as_uint(f);
    return ((int)u >= 0) ? (u | 0x80000000u) : ~u;
}
__device__ __forceinline__ float iord32(unsigned u) {
    unsigned s = (u & 0x80000000u) ? (u & 0x7FFFFFFFu) : ~u;
    return __uint_as_float(s);
}
__device__ __forceinline__ u64 mkkey(unsigned o, int m) {
    return ((u64)o << 32) | (unsigned)(~m);
}

// Dual-stream bitonic sort, descending by u64 key. Element e = lane + 64*i.
// After sort, reg 0 lane r holds rank-r element.
template <int R>
__device__ __forceinline__ void sort2_desc(u64* A, u64* B, int lane) {
    const int NEL = R * 64;
    #pragma unroll
    for (int k = 2; k <= NEL; k <<= 1) {
        #pragma unroll
        for (int j = k >> 1; j >= 1; j >>= 1) {
            if (j >= 64) {
                const int rj = j >> 6;
                #pragma unroll
                for (int i = 0; i < R; ++i) {
                    if ((i & rj) == 0) {
                        const int e = lane + 64 * i;
                        const bool wm = ((e & k) == 0);
                        u64 x = A[i], y = A[i ^ rj];
                        u64 mx = x > y ? x : y, mn = x > y ? y : x;
                        A[i] = wm ? mx : mn; A[i ^ rj] = wm ? mn : mx;
                        x = B[i]; y = B[i ^ rj];
                        mx = x > y ? x : y; mn = x > y ? y : x;
                        B[i] = wm ? mx : mn; B[i ^ rj] = wm ? mn : mx;
                    }
                }
            } else {
                #pragma unroll
                for (int i = 0; i < R; ++i) {
                    const int e = lane + 64 * i;
                    const bool wm = ((e & j) == 0) == ((e & k) == 0);
                    const u64 oa = __shfl_xor(A[i], j);
                    const u64 ob = __shfl_xor(B[i], j);
                    const u64 mxa = A[i] > oa ? A[i] : oa;
                    const u64 mna = A[i] > oa ? oa : A[i];
                    A[i] = wm ? mxa : mna;
                    const u64 mxb = B[i] > ob ? B[i] : ob;
                    const u64 mnb = B[i] > ob ? ob : B[i];
                    B[i] = wm ? mxb : mnb;
                }
            }
        }
    }
}

// Exact rare-path (Ctot > 128, statistically never taken). RECOMPUTES the
// distances from LDS so the hot path does not keep ord[] live across the
// sort. Returns rank-`lane` winner for lane<32.
__device__ __noinline__ u64 knn_fallback(const float* xs, const float* xxs,
                                         int n, int lane) {
    const float4* xs4  = (const float4*)xs;
    const float4* xxs4 = (const float4*)xxs;
    float4 acc[4];
    #pragma unroll
    for (int c = 0; c < 4; ++c) acc[c] = make_float4(0.f, 0.f, 0.f, 0.f);
    for (int d = 0; d < DFEAT; ++d) {
        const float xnd = xs[d * NPTS + n];
        #pragma unroll
        for (int c = 0; c < 4; ++c) {
            const float4 t = xs4[d * 256 + c * 64 + lane];
            acc[c].x = fmaf(t.x, xnd, acc[c].x);
            acc[c].y = fmaf(t.y, xnd, acc[c].y);
            acc[c].z = fmaf(t.z, xnd, acc[c].z);
            acc[c].w = fmaf(t.w, xnd, acc[c].w);
        }
    }
    const float xxn = xxs[n];
    unsigned ord[16];
    #pragma unroll
    for (int c = 0; c < 4; ++c) {
        const float4 xm = xxs4[c * 64 + lane];
        ord[c * 4 + 0] = ord32((2.f * acc[c].x - xxn) - xm.x);
        ord[c * 4 + 1] = ord32((2.f * acc[c].y - xxn) - xm.y);
        ord[c * 4 + 2] = ord32((2.f * acc[c].z - xxn) - xm.z);
        ord[c * 4 + 3] = ord32((2.f * acc[c].w - xxn) - xm.w);
    }
    u64 W = ~0ULL, win = 0ULL;
    for (int it = 0; it < 32; ++it) {
        u64 best = 0ULL;
        #pragma unroll
        for (int i = 0; i < 16; ++i) {
            const int m = (i >> 2) * 256 + lane * 4 + (i & 3);
            const u64 k = mkkey(ord[i], m);
            if (k < W && k > best) best = k;
        }
        #pragma unroll
        for (int off = 32; off >= 1; off >>= 1) {
            const u64 o = __shfl_xor(best, off);
            best = o > best ? o : best;
        }
        win = (lane == it) ? best : win;
        W = best;
    }
    return win;
}

// ---------------------------------------------------------------------------
// Kernel 1: per-row KNN, 2 rows per wave (the proven spill-free envelope).
// Threshold = 32nd largest of the 64 lane maxima, found by BALLOT BISECTION
// (pure VALU/SALU; zero DS-pipe ops; bit-exact: largest T with
// popcount(lanes with max >= T) >= 32). Exact u64 candidate sort unchanged.
// grid 256 (32 b x 8 chunks), block 1024 (16 waves x 8 rows), LDS 120KB.
// ---------------------------------------------------------------------------
__global__ __launch_bounds__(1024)
__attribute__((amdgpu_waves_per_eu(4, 4)))
void knn_kernel(
        const float* __restrict__ x,
        int* __restrict__ idx_ws, float* __restrict__ dist_ws,
        float* __restrict__ sub_ws) {
    extern __shared__ float smem[];
    float* xs  = smem;                         // [21][1024]
    float* xxs = smem + DFEAT * NPTS;          // [1024]
    u64* cand  = (u64*)(smem + (DFEAT + 1) * NPTS);  // [16][2][128]

    const int tid  = threadIdx.x;
    const int lane = tid & 63;
    const int w    = tid >> 6;
    const int b      = blockIdx.x >> 3;
    const int nchunk = blockIdx.x & 7;

    const float* xb = x + (size_t)b * DFEAT * NPTS;
    for (int i = tid; i < DFEAT * NPTS; i += 1024) xs[i] = xb[i];
    __syncthreads();
    {
        float s = 0.f;
        #pragma unroll
        for (int d = 0; d < DFEAT; ++d) { float v = xs[d * NPTS + tid]; s = fmaf(v, v, s); }
        xxs[tid] = s;
    }
    __syncthreads();

    u64* cwA = cand + (w * 2 + 0) * 128;
    u64* cwB = cand + (w * 2 + 1) * 128;
    const float4* xs4  = (const float4*)xs;
    const float4* xxs4 = (const float4*)xxs;

    const int nbase = nchunk * 128 + w * 8;

    for (int rp = 0; rp < 4; ++rp) {
        const int na = nbase + rp * 2;   // even
        const int nb = na + 1;

        // ---- distances for the pair; m-side float4 reads shared ----
        float4 accA[4], accB[4];
        #pragma unroll
        for (int c = 0; c < 4; ++c) {
            accA[c] = make_float4(0.f, 0.f, 0.f, 0.f);
            accB[c] = make_float4(0.f, 0.f, 0.f, 0.f);
        }
        for (int d = 0; d < DFEAT; ++d) {
            const float2 xn2 = *(const float2*)(xs + d * NPTS + na);
            const float xda = xn2.x;
            const float xdb = xn2.y;
            #pragma unroll
            for (int c = 0; c < 4; ++c) {
                const float4 t = xs4[d * 256 + c * 64 + lane];
                accA[c].x = fmaf(t.x, xda, accA[c].x);
                accA[c].y = fmaf(t.y, xda, accA[c].y);
                accA[c].z = fmaf(t.z, xda, accA[c].z);
                accA[c].w = fmaf(t.w, xda, accA[c].w);
                accB[c].x = fmaf(t.x, xdb, accB[c].x);
                accB[c].y = fmaf(t.y, xdb, accB[c].y);
                accB[c].z = fmaf(t.z, xdb, accB[c].z);
                accB[c].w = fmaf(t.w, xdb, accB[c].w);
            }
        }
        const float xxna = xxs[na], xxnb = xxs[nb];
        unsigned ordA[16], ordB[16];
        #pragma unroll
        for (int c = 0; c < 4; ++c) {
            const float4 xm = xxs4[c * 64 + lane];
            ordA[c * 4 + 0] = ord32((2.f * accA[c].x - xxna) - xm.x);
            ordA[c * 4 + 1] = ord32((2.f * accA[c].y - xxna) - xm.y);
            ordA[c * 4 + 2] = ord32((2.f * accA[c].z - xxna) - xm.z);
            ordA[c * 4 + 3] = ord32((2.f * accA[c].w - xxna) - xm.w);
            ordB[c * 4 + 0] = ord32((2.f * accB[c].x - xxnb) - xm.x);
            ordB[c * 4 + 1] = ord32((2.f * accB[c].y - xxnb) - xm.y);
            ordB[c * 4 + 2] = ord32((2.f * accB[c].z - xxnb) - xm.z);
            ordB[c * 4 + 3] = ord32((2.f * accB[c].w - xxnb) - xm.w);
        }

        // ---- per-lane max VALUE (threshold needs no index) ----
        unsigned va = ordA[0], vb = ordB[0];
        #pragma unroll
        for (int i = 1; i < 16; ++i) {
            va = ordA[i] > va ? ordA[i] : va;
            vb = ordB[i] > vb ? ordB[i] : vb;
        }

        // ---- threshold via ballot bisection (no DS ops; SGPR result) ----
        // T = largest value with >=32 lanes' max >= T  ==  32nd largest
        // of the 64 lane maxima (bit-exact vs the bitonic it replaces).
        unsigned Ta = 0u, Tb = 0u;
        #pragma unroll
        for (int bit = 31; bit >= 0; --bit) {
            const unsigned ca2 = Ta | (1u << bit);
            const unsigned cb2 = Tb | (1u << bit);
            const u64 ba = __ballot(va >= ca2);
            const u64 bb = __ballot(vb >= cb2);
            if (__popcll(ba) >= 32) Ta = ca2;
            if (__popcll(bb) >= 32) Tb = cb2;
        }

        // ---- count + exclusive prefix for compaction (u32 compares) ----
        int ca = 0, cb = 0;
        #pragma unroll
        for (int i = 0; i < 16; ++i) {
            ca += (ordA[i] >= Ta) ? 1 : 0;
            cb += (ordB[i] >= Tb) ? 1 : 0;
        }
        int sa = ca, sb = cb;
        #pragma unroll
        for (int off = 1; off < 64; off <<= 1) {
            const int t2a = __shfl_up(sa, off);
            const int t2b = __shfl_up(sb, off);
            if (lane >= off) { sa += t2a; sb += t2b; }
        }
        const int baseA = sa - ca, baseB = sb - cb;
        const int CtA = __shfl(sa, 63), CtB = __shfl(sb, 63);

        // ---- compact candidates to LDS; ordA/ordB die here ----
        {
            int p = baseA;
            #pragma unroll
            for (int i = 0; i < 16; ++i) {
                const int m = (i >> 2) * 256 + lane * 4 + (i & 3);
                if (ordA[i] >= Ta) { if (p < 128) cwA[p] = mkkey(ordA[i], m); ++p; }
            }
            p = baseB;
            #pragma unroll
            for (int i = 0; i < 16; ++i) {
                const int m = (i >> 2) * 256 + lane * 4 + (i & 3);
                if (ordB[i] >= Tb) { if (p < 128) cwB[p] = mkkey(ordB[i], m); ++p; }
            }
        }
        __asm__ volatile("s_waitcnt lgkmcnt(0)" ::: "memory");

        // ---- adaptive dual bitonic top-32 (exact order) ----
        u64 keyA, keyB;
        if (CtA <= 128 && CtB <= 128) {
            if (CtA <= 64 && CtB <= 64) {
                u64 a0 = (lane < CtA) ? cwA[lane] : 0ULL;
                u64 b0 = (lane < CtB) ? cwB[lane] : 0ULL;
                sort2_desc<1>(&a0, &b0, lane);
                keyA = a0; keyB = b0;
            } else {
                u64 a[2], bb2[2];
                #pragma unroll
                for (int i = 0; i < 2; ++i) {
                    const int ci = lane + 64 * i;
                    a[i]   = (ci < CtA) ? cwA[ci] : 0ULL;
                    bb2[i] = (ci < CtB) ? cwB[ci] : 0ULL;
                }
                sort2_desc<2>(a, bb2, lane);
                keyA = a[0]; keyB = bb2[0];
            }
        } else {
            keyA = knn_fallback(xs, xxs, na, lane);
            keyB = knn_fallback(xs, xxs, nb, lane);
        }

        // ---- epilogue: lane r (<32) holds rank-r neighbor ----
        const int   mA = (int)(~(unsigned)keyA);
        const int   mB = (int)(~(unsigned)keyB);
        const float pdA = iord32((unsigned)(keyA >> 32));
        const float pdB = iord32((unsigned)(keyB >> 32));
        if (lane < KSEL) {
            const size_t oA = ((size_t)(b * NPTS + na)) * KSEL + lane;
            const size_t oB = ((size_t)(b * NPTS + nb)) * KSEL + lane;
            idx_ws[oA]  = mA;          idx_ws[oB]  = mB;
            dist_ws[oA] = -pdA;        dist_ws[oB] = -pdB;
            sub_ws[oA]  = 0.5f * ((pdA + xxs[mA]) + xxna);
            sub_ws[oB]  = 0.5f * ((pdB + xxs[mB]) + xxnb);
        }
    }
}

// ---------------------------------------------------------------------------
// Kernel 2: partial Gram of q = sub^2 over 128-row chunks.
// grid 256 (b x 8), block 256 (k = t/8, 4 j's per thread).
// ---------------------------------------------------------------------------
__global__ __launch_bounds__(256) void norm_part_kernel(
        const float* __restrict__ sub_ws, float* __restrict__ npart) {
    __shared__ float qS[128 * 33];
    const int tid = threadIdx.x;
    const int bc = blockIdx.x;
    const float* sb = sub_ws + (size_t)bc * 128 * KSEL;
    for (int i = tid; i < 128 * 32; i += 256) {
        const float v = sb[i];
        qS[(i >> 5) * 33 + (i & 31)] = v * v;
    }
    __syncthreads();
    const int k = tid >> 3, jg = tid & 7;
    float a0 = 0.f, a1 = 0.f, a2 = 0.f, a3 = 0.f;
    for (int n = 0; n < 128; ++n) {
        const float qk = qS[n * 33 + k];
        a0 = fmaf(qk, qS[n * 33 + jg], a0);
        a1 = fmaf(qk, qS[n * 33 + jg + 8], a1);
        a2 = fmaf(qk, qS[n * 33 + jg + 16], a2);
        a3 = fmaf(qk, qS[n * 33 + jg + 24], a3);
    }
    float* op = npart + (size_t)bc * 1024 + k * 32 + jg;
    op[0] = a0; op[8] = a1; op[16] = a2; op[24] = a3;
}

// ---------------------------------------------------------------------------
// Kernel 3 (combo): blocks 0..31 = norm_combine (recip); blocks 32..159 =
// uc[b,n,o] = sum_d w_up[o,d] x[b,d,n]. One fewer launch (R7-validated).
// grid 160, block 1024.
// ---------------------------------------------------------------------------
__global__ __launch_bounds__(1024) void combo_kernel(
        const float* __restrict__ npart, float* __restrict__ recip_ws,
        const float* __restrict__ x, const float* __restrict__ w_up,
        float* __restrict__ uc_ws) {
    __shared__ float wS[NOUT * DFEAT];
    const int bid = blockIdx.x;
    const int tid = threadIdx.x;
    if (bid < 32) {
        const int b = bid;
        float s = 0.f;
        #pragma unroll
        for (int c = 0; c < 8; ++c)
            s += npart[(size_t)(b * 8 + c) * 1024 + tid];
        recip_ws[(size_t)b * NPTS + tid] = 1.0f / fmaxf(sqrtf(s), 1e-12f);
    } else {
        const int lane = tid & 63, w = tid >> 6;
        const int ub = bid - 32;
        const int b  = ub >> 2;
        const int n0 = (ub & 3) * 256 + w * 16;
        for (int i = tid; i < NOUT * DFEAT; i += 1024) wS[i] = w_up[i];
        __syncthreads();
        float wr[DFEAT];
        #pragma unroll
        for (int d = 0; d < DFEAT; ++d) wr[d] = wS[lane * DFEAT + d];
        const float* xb = x + (size_t)b * DFEAT * NPTS;
        for (int g = 0; g < 4; ++g) {
            const int nn = __builtin_amdgcn_readfirstlane(n0 + g * 4);
            float a0 = 0.f, a1 = 0.f, a2 = 0.f, a3 = 0.f;
            #pragma unroll
            for (int d = 0; d < DFEAT; ++d) {
                const float* xp = xb + d * NPTS + nn;
                const float wd = wr[d];
                a0 = fmaf(wd, xp[0], a0);
                a1 = fmaf(wd, xp[1], a1);
                a2 = fmaf(wd, xp[2], a2);
                a3 = fmaf(wd, xp[3], a3);
            }
            float* op = uc_ws + ((size_t)(b * NPTS) + nn) * NOUT + lane;
            op[0 * NOUT] = a0; op[1 * NOUT] = a1;
            op[2 * NOUT] = a2; op[3 * NOUT] = a3;
        }
    }
}

// ---------------------------------------------------------------------------
// Kernel 4: gm_red + BN1/BN2 f64 partial sums. 32 rows per block.
// grid 1024 (b x 32), block 256.
// ---------------------------------------------------------------------------
__global__ __launch_bounds__(256) void gmred_kernel(
        const float* __restrict__ sub_ws, const float* __restrict__ dist_ws,
        const float* __restrict__ recip_ws, const float* __restrict__ w_gm,
        float* __restrict__ gmred_ws, double* __restrict__ part12) {
    __shared__ float subS[32 * 32];
    __shared__ float subWS[32 * 32];
    __shared__ double redS[4][4];

    const int tid = threadIdx.x;
    const int b   = blockIdx.x >> 5;
    const int n0  = (blockIdx.x & 31) * 32;

    {
        const float4 wv = ((const float4*)w_gm)[tid & 7];
        const float4 sv = ((const float4*)(sub_ws + ((size_t)(b * NPTS + n0)) * KSEL))[tid];
        ((float4*)subS)[tid] = sv;
        float4 t;
        t.x = sv.x * wv.x; t.y = sv.y * wv.y; t.z = sv.z * wv.z; t.w = sv.w * wv.w;
        ((float4*)subWS)[tid] = t;
    }
    const int k = tid & 31, rg = tid >> 5;
    float rk[32];
    {
        const float4* rp = (const float4*)(recip_ws + (size_t)b * NPTS + k * 32);
        #pragma unroll
        for (int c4 = 0; c4 < 8; ++c4) {
            const float4 v = rp[c4];
            rk[c4 * 4 + 0] = v.x; rk[c4 * 4 + 1] = v.y;
            rk[c4 * 4 + 2] = v.z; rk[c4 * 4 + 3] = v.w;
        }
    }
    __syncthreads();

    float sacc[4] = {0.f, 0.f, 0.f, 0.f};
    const float4* swp = (const float4*)subWS;
    #pragma unroll
    for (int c4 = 0; c4 < 8; ++c4) {
        #pragma unroll
        for (int i = 0; i < 4; ++i) {
            const float4 sw = swp[(rg * 4 + i) * 8 + c4];
            sacc[i] = fmaf(sw.x, rk[c4 * 4 + 0], sacc[i]);
            sacc[i] = fmaf(sw.y, rk[c4 * 4 + 1], sacc[i]);
            sacc[i] = fmaf(sw.z, rk[c4 * 4 + 2], sacc[i]);
            sacc[i] = fmaf(sw.w, rk[c4 * 4 + 3], sacc[i]);
        }
    }

    double s1 = 0, s2 = 0, s3 = 0, s4 = 0;
    #pragma unroll
    for (int i = 0; i < 4; ++i) {
        const int rl = rg * 4 + i;
        const float g = subS[rl * 32 + k] * sacc[i];
        const size_t row = (size_t)(b * NPTS + n0 + rl);
        gmred_ws[row * KSEL + k] = g;
        const float dv = dist_ws[row * KSEL + k];
        s1 += (double)dv; s2 = fma((double)dv, (double)dv, s2);
        s3 += (double)g;  s4 = fma((double)g, (double)g, s4);
    }
    #pragma unroll
    for (int off = 32; off >= 1; off >>= 1) {
        s1 += __shfl_xor(s1, off);
        s2 += __shfl_xor(s2, off);
        s3 += __shfl_xor(s3, off);
        s4 += __shfl_xor(s4, off);
    }
    if ((tid & 63) == 0) {
        const int wv = tid >> 6;
        redS[wv][0] = s1; redS[wv][1] = s2; redS[wv][2] = s3; redS[wv][3] = s4;
    }
    __syncthreads();
    if (tid == 0) {
        double a0 = 0, a1 = 0, a2 = 0, a3 = 0;
        #pragma unroll
        for (int wv = 0; wv < 4; ++wv) {
            a0 += redS[wv][0]; a1 += redS[wv][1]; a2 += redS[wv][2]; a3 += redS[wv][3];
        }
        part12[(size_t)blockIdx.x * 4 + 0] = a0;
        part12[(size_t)blockIdx.x * 4 + 1] = a1;
        part12[(size_t)blockIdx.x * 4 + 2] = a2;
        part12[(size_t)blockIdx.x * 4 + 3] = a3;
    }
}

// ---------------------------------------------------------------------------
// Kernel 5: reduce BN1/BN2 partials -> folded scale/offset consts. grid 1.
// ---------------------------------------------------------------------------
__global__ __launch_bounds__(256) void reduce12_kernel(
        const double* __restrict__ part12, int nblocks,
        const float* __restrict__ w_dist,
        const float* __restrict__ g1, const float* __restrict__ b1,
        const float* __restrict__ g2, const float* __restrict__ b2,
        float* __restrict__ consts) {
    __shared__ double S[256][4];
    const int t = threadIdx.x;
    double a0 = 0, a1 = 0, a2 = 0, a3 = 0;
    for (int i = t; i < nblocks; i += 256) {
        a0 += part12[(size_t)i * 4 + 0];
        a1 += part12[(size_t)i * 4 + 1];
        a2 += part12[(size_t)i * 4 + 2];
        a3 += part12[(size_t)i * 4 + 3];
    }
    S[t][0] = a0; S[t][1] = a1; S[t][2] = a2; S[t][3] = a3;
    __syncthreads();
    for (int off = 128; off >= 1; off >>= 1) {
        if (t < off) {
            S[t][0] += S[t + off][0]; S[t][1] += S[t + off][1];
            S[t][2] += S[t + off][2]; S[t][3] += S[t + off][3];
        }
        __syncthreads();
    }
    if (t == 0) {
        const double M = (double)BATCH * NPTS * KSEL;
        const double E1 = S[0][0] / M, E2 = S[0][1] / M;
        const double wd = (double)w_dist[0];
        const double mean1 = wd * E1;
        const double var1  = wd * wd * (E2 - E1 * E1);
        const double istd1 = 1.0 / sqrt(var1 + 1e-5);
        consts[0] = (float)(wd * istd1 * (double)g1[0]);
        consts[1] = (float)((double)b1[0] - mean1 * istd1 * (double)g1[0]);
        const double F1 = S[0][2] / M, F2 = S[0][3] / M;
        const double var2  = F2 - F1 * F1;
        const double istd2 = 1.0 / sqrt(var2 + 1e-5);
        consts[2] = (float)(istd2 * (double)g2[0]);
        consts[3] = (float)((double)b2[0] - F1 * istd2 * (double)g2[0]);
    }
}

// ---------------------------------------------------------------------------
// Kernel 6: fused gate compute (LDS broadcast, no shuffles) + BN3 partial
// stats. Writes gate_ws for final. grid 2048 (XCD-swizzled), block 256.
// ---------------------------------------------------------------------------
__global__ __launch_bounds__(256) void gate_stats_kernel(
        const float* __restrict__ dist_ws, const float* __restrict__ gmred_ws,
        const int* __restrict__ idx_ws, const float* __restrict__ uc_ws,
        const float* __restrict__ consts,
        float* __restrict__ gate_ws, double* __restrict__ part3) {
    __shared__ float gS[4][32];
    const int tid = threadIdx.x, lane = tid & 63, w = tid >> 6;
    const int bid = blockIdx.x;
    const int lbid = (bid & 7) * 256 + (bid >> 3);   // b-groups pinned per XCD
    const int b  = lbid >> 6;
    const int n0 = (lbid & 63) * 16;
    const float A1 = consts[0], C1 = consts[1], A2 = consts[2], C2 = consts[3];
    const float* ucb = uc_ws + (size_t)b * NPTS * NOUT;
    double sum = 0.0, ssq = 0.0;
    for (int rr = 0; rr < 4; ++rr) {
        const int n = __builtin_amdgcn_readfirstlane(n0 + w * 4 + rr);
        const int row = b * NPTS + n;
        if (lane < KSEL) {
            const size_t rbase = (size_t)row * KSEL + lane;
            const float dv = dist_ws[rbase];
            const float gv = gmred_ws[rbase];
            const float w1 = 1.f / (1.f + __expf(-fmaf(dv, A1, C1)));
            const float w2 = 1.f / (1.f + __expf(-fmaf(gv, A2, C2)));
            const float gate = w1 * w2;
            gate_ws[rbase] = gate;
            gS[w][lane] = gate;
        }
        __asm__ volatile("s_waitcnt lgkmcnt(0)" ::: "memory");
        const int* ip = idx_ws + (size_t)row * KSEL;
        const float ucr = ucb[(size_t)n * NOUT + lane];
        float fs = 0.f, fq = 0.f;
        #pragma unroll
        for (int k = 0; k < KSEL; ++k) {
            const float gk = gS[w][k];
            const int   jk = ip[k];
            const float ucn = ucb[(size_t)jk * NOUT + lane];
            const float up  = fmaf(gk, ucn - ucr, ucr);
            fs += up;
            fq = fmaf(up, up, fq);
        }
        sum += (double)fs; ssq += (double)fq;
    }
    __shared__ double p3[4][NOUT][2];
    p3[w][lane][0] = sum; p3[w][lane][1] = ssq;
    __syncthreads();
    if (w == 0) {
        const double s = p3[0][lane][0] + p3[1][lane][0] + p3[2][lane][0] + p3[3][lane][0];
        const double q = p3[0][lane][1] + p3[1][lane][1] + p3[2][lane][1] + p3[3][lane][1];
        part3[((size_t)bid * NOUT + lane) * 2 + 0] = s;
        part3[((size_t)bid * NOUT + lane) * 2 + 1] = q;
    }
}

// ---------------------------------------------------------------------------
// Kernel 7: reduce BN3 partials -> per-channel A/C. grid 64 (one per o).
// ---------------------------------------------------------------------------
__global__ __launch_bounds__(256) void reduce3_kernel(
        const double* __restrict__ part3,
        const float* __restrict__ g3, const float* __restrict__ b3,
        float* __restrict__ consts3) {
    const int o = blockIdx.x, t = threadIdx.x;
    double s = 0, q = 0;
    for (int i = t; i < 2048; i += 256) {
        s += part3[((size_t)i * NOUT + o) * 2 + 0];
        q += part3[((size_t)i * NOUT + o) * 2 + 1];
    }
    __shared__ double S[256][2];
    S[t][0] = s; S[t][1] = q;
    __syncthreads();
    for (int off = 128; off >= 1; off >>= 1) {
        if (t < off) { S[t][0] += S[t + off][0]; S[t][1] += S[t + off][1]; }
        __syncthreads();
    }
    if (t == 0) {
        const double M = (double)BATCH * NPTS * KSEL;
        const double mean = S[0][0] / M;
        const double var  = S[0][1] / M - mean * mean;
        const double istd = 1.0 / sqrt(var + 1e-5);
        consts3[o]        = (float)(istd * (double)g3[o]);
        consts3[64 + o]   = (float)((double)b3[o] - mean * istd * (double)g3[o]);
    }
}

// ---------------------------------------------------------------------------
// Kernel 8: out[b,o,n] = mean_k lrelu(up*A[o]+C[o]). LDS-staged coalesced
// float4 stores. grid 2048 (XCD-swizzled), block 256.
// ---------------------------------------------------------------------------
__global__ __launch_bounds__(256) void final_kernel(
        const float* __restrict__ gate_ws, const int* __restrict__ idx_ws,
        const float* __restrict__ uc_ws, const float* __restrict__ consts3,
        float* __restrict__ out) {
    __shared__ float buf[16 * 65];
    const int tid = threadIdx.x, lane = tid & 63, w = tid >> 6;
    const int bid = blockIdx.x;
    const int lbid = (bid & 7) * 256 + (bid >> 3);
    const int b  = lbid >> 6;
    const int n0 = (lbid & 63) * 16;
    const float* ucb = uc_ws + (size_t)b * NPTS * NOUT;
    const float A = consts3[lane], C = consts3[64 + lane];
    for (int rr = 0; rr < 4; ++rr) {
        const int n = __builtin_amdgcn_readfirstlane(n0 + w * 4 + rr);
        const int row = b * NPTS + n;
        const float* gp = gate_ws + (size_t)row * KSEL;
        const int*   ip = idx_ws  + (size_t)row * KSEL;
        const float ucr = ucb[(size_t)n * NOUT + lane];
        float acc = 0.f;
        #pragma unroll
        for (int k = 0; k < KSEL; ++k) {
            const float gk = gp[k];
            const int   jk = ip[k];
            const float ucn = ucb[(size_t)jk * NOUT + lane];
            const float up  = fmaf(gk, ucn - ucr, ucr);
            float z = fmaf(up, A, C);
            z = (z >= 0.f) ? z : 0.02f * z;
            acc += z;
        }
        buf[(w * 4 + rr) * 65 + lane] = acc * (1.f / 32.f);
    }
    __syncthreads();
    const int o = tid >> 2, g = tid & 3;
    float4 v;
    v.x = buf[(g * 4 + 0) * 65 + o];
    v.y = buf[(g * 4 + 1) * 65 + o];
    v.z = buf[(g * 4 + 2) * 65 + o];
    v.w = buf[(g * 4 + 3) * 65 + o];
    float4* op = (float4*)(out + (size_t)b * NOUT * NPTS + (size_t)o * NPTS + n0);
    op[g] = v;
}

// ---------------------------------------------------------------------------
extern "C" void kernel_launch(void* const* d_in, const int* in_sizes, int n_in,
                              void* d_out, int out_size, void* d_ws, size_t ws_size,
                              hipStream_t stream) {
    const float* x      = (const float*)d_in[0];
    const float* w_dist = (const float*)d_in[2];
    const float* g1     = (const float*)d_in[3];
    const float* b1     = (const float*)d_in[4];
    const float* w_gm   = (const float*)d_in[5];
    const float* g2     = (const float*)d_in[6];
    const float* b2     = (const float*)d_in[7];
    const float* w_up   = (const float*)d_in[8];
    const float* g3     = (const float*)d_in[9];
    const float* b3     = (const float*)d_in[10];
    float* out = (float*)d_out;

    char* ws = (char*)d_ws;
    int*    idx_ws   = (int*)(ws + 0);                      //  0- 4 MB
    float*  dist_ws  = (float*)(ws + ((size_t)4 << 20));    //  4- 8 MB
    float*  sub_ws   = (float*)(ws + ((size_t)8 << 20));    //  8-12 MB (part3 later)
    float*  gmred_ws = (float*)(ws + ((size_t)12 << 20));   // 12-16 MB
    float*  gate_ws  = (float*)(ws + ((size_t)16 << 20));   // 16-20 MB (npart early)
    float*  uc_ws    = (float*)(ws + ((size_t)20 << 20));   // 20-28 MB
    float*  recip_ws = (float*)(ws + ((size_t)28 << 20));
    double* part12   = (double*)(ws + ((size_t)28 << 20) + 0x20000);
    float*  consts   = (float*)(ws + ((size_t)28 << 20) + 0x60000);
    float*  consts3  = consts + 8;
    float*  npart    = gate_ws;            // consumed before gate_stats writes
    double* part3    = (double*)sub_ws;    // sub_ws retired after gmred reads it

    const int knn_lds = (DFEAT + 1) * NPTS * 4 + 16 * 2 * 128 * 8;  // 120 KB

    knn_kernel<<<dim3(256), dim3(1024), knn_lds, stream>>>(x, idx_ws, dist_ws, sub_ws);
    norm_part_kernel<<<dim3(256), dim3(256), 0, stream>>>(sub_ws, npart);
    combo_kernel<<<dim3(160), dim3(1024), 0, stream>>>(npart, recip_ws, x, w_up, uc_ws);
    gmred_kernel<<<dim3(1024), dim3(256), 0, stream>>>(sub_ws, dist_ws, recip_ws, w_gm,
                                                       gmred_ws, part12);
    reduce12_kernel<<<dim3(1), dim3(256), 0, stream>>>(part12, 1024, w_dist, g1, b1, g2, b2,
                                                       consts);
    gate_stats_kernel<<<dim3(2048), dim3(256), 0, stream>>>(dist_ws, gmred_ws, idx_ws, uc_ws,
                                                            consts, gate_ws, part3);
    reduce3_kernel<<<dim3(64), dim3(256), 0, stream>>>(part3, g3, b3, consts3);
    final_kernel<<<dim3(2048), dim3(256), 0, stream>>>(gate_ws, idx_ws, uc_ws, consts3, out);
}